// Round 1
// baseline (4665.346 us; speedup 1.0000x reference)
//
#include <hip/hip_runtime.h>

#define NN 50000
#define NE 600000
#define HD 128
#define OUTF 64
#define NL 4
#define NG 128
#define BN_EPS 1e-5f

// ---------------------------------------------------------------------------
// GEMM: C[NN,128] = act( (A (+Agg)) @ W + bias ), W is [128,128] row-major.
// Block: 256 threads, 32-row tile. LDS: W (64KB) + A-tile (16KB) = 80KB
// -> 2 blocks/CU. Each thread: 4 rows x 4 cols register tile.
// STATS: fused BatchNorm partial sums/sumsq (per-column) via LDS + atomics.
// ---------------------------------------------------------------------------
template<bool ADD_AGG, bool RELU, bool STATS>
__global__ __launch_bounds__(256) void gemm128(
    const float* __restrict__ A, const float* __restrict__ Agg,
    const float* __restrict__ W, const float* __restrict__ bias,
    float* __restrict__ C, float* __restrict__ sums, float* __restrict__ sumsq)
{
    __shared__ float Ws[HD * HD];
    __shared__ float As[32 * HD];
    const int t = threadIdx.x;
    const int row0 = blockIdx.x * 32;

    #pragma unroll 8
    for (int i = t; i < HD * HD; i += 256) Ws[i] = W[i];

    for (int i = t; i < 32 * HD; i += 256) {
        int r = row0 + (i >> 7);
        float v = 0.f;
        if (r < NN) {
            v = A[(size_t)r * HD + (i & 127)];
            if (ADD_AGG) v += Agg[(size_t)r * HD + (i & 127)];
        }
        As[i] = v;
    }
    __syncthreads();

    const int tc = t & 31;   // column group: cols tc*4 .. tc*4+3
    const int tr = t >> 5;   // row group:    rows tr*4 .. tr*4+3

    float acc[4][4];
    #pragma unroll
    for (int i = 0; i < 4; i++)
        #pragma unroll
        for (int j = 0; j < 4; j++) acc[i][j] = 0.f;

    const float4* WsV = reinterpret_cast<const float4*>(Ws);
    #pragma unroll 4
    for (int k = 0; k < HD; k++) {
        float4 w = WsV[k * 32 + tc];          // ds_read_b128, conflict-free
        #pragma unroll
        for (int i = 0; i < 4; i++) {
            float a = As[(tr * 4 + i) * HD + k];  // 2 distinct addrs/wave: free
            acc[i][0] += a * w.x;
            acc[i][1] += a * w.y;
            acc[i][2] += a * w.z;
            acc[i][3] += a * w.w;
        }
    }

    const float b0 = bias[tc * 4 + 0], b1 = bias[tc * 4 + 1];
    const float b2 = bias[tc * 4 + 2], b3 = bias[tc * 4 + 3];
    float vals[4][4];
    #pragma unroll
    for (int i = 0; i < 4; i++) {
        int r = row0 + tr * 4 + i;
        float4 v;
        v.x = acc[i][0] + b0; v.y = acc[i][1] + b1;
        v.z = acc[i][2] + b2; v.w = acc[i][3] + b3;
        if (RELU) {
            v.x = fmaxf(v.x, 0.f); v.y = fmaxf(v.y, 0.f);
            v.z = fmaxf(v.z, 0.f); v.w = fmaxf(v.w, 0.f);
        }
        vals[i][0] = v.x; vals[i][1] = v.y; vals[i][2] = v.z; vals[i][3] = v.w;
        if (r < NN)
            *reinterpret_cast<float4*>(&C[(size_t)r * HD + tc * 4]) = v;
    }

    if (STATS) {
        __syncthreads();   // everyone done reading As; reuse it for reduction
        float s[4] = {0, 0, 0, 0}, q[4] = {0, 0, 0, 0};
        #pragma unroll
        for (int i = 0; i < 4; i++) {
            int r = row0 + tr * 4 + i;
            if (r < NN) {
                #pragma unroll
                for (int j = 0; j < 4; j++) {
                    float v = vals[i][j];
                    s[j] += v; q[j] += v * v;
                }
            }
        }
        #pragma unroll
        for (int j = 0; j < 4; j++) {
            As[tr * HD + tc * 4 + j]          = s[j];
            As[8 * HD + tr * HD + tc * 4 + j] = q[j];
        }
        __syncthreads();
        if (t < HD) {
            float ss = 0.f, qq = 0.f;
            #pragma unroll
            for (int g = 0; g < 8; g++) {
                ss += As[g * HD + t];
                qq += As[8 * HD + g * HD + t];
            }
            atomicAdd(&sums[t], ss);
            atomicAdd(&sumsq[t], qq);
        }
    }
}

// ---------------------------------------------------------------------------
// Edge scatter-add: agg[dst] += h[src]. 8 edges per 256-thread block,
// each thread moves one float4 (4 scalar atomics).
// ---------------------------------------------------------------------------
__global__ __launch_bounds__(256) void scatter_kernel(
    const float* __restrict__ h, const int* __restrict__ src,
    const int* __restrict__ dst, float* __restrict__ agg)
{
    int idx = blockIdx.x * 256 + threadIdx.x;
    int e = idx >> 5;
    int f0 = (idx & 31) * 4;
    if (e >= NE) return;
    int s = src[e];
    int d = dst[e];
    const float4 v = *reinterpret_cast<const float4*>(&h[(size_t)s * HD + f0]);
    float* ap = &agg[(size_t)d * HD + f0];
    atomicAdd(ap + 0, v.x);
    atomicAdd(ap + 1, v.y);
    atomicAdd(ap + 2, v.z);
    atomicAdd(ap + 3, v.w);
}

// ---------------------------------------------------------------------------
// BN finalize: scale/shift from accumulated sums/sumsq (population variance).
// ---------------------------------------------------------------------------
__global__ void bn_finalize_kernel(
    const float* __restrict__ sums, const float* __restrict__ sumsq,
    const float* __restrict__ gamma, const float* __restrict__ beta,
    float* __restrict__ scale, float* __restrict__ shift)
{
    int c = threadIdx.x;
    const float invN = 1.f / (float)NN;
    float mean = sums[c] * invN;
    float var = sumsq[c] * invN - mean * mean;
    float inv = rsqrtf(var + BN_EPS);
    float sc = gamma[c] * inv;
    scale[c] = sc;
    shift[c] = beta[c] - mean * sc;
}

// h = relu(h * scale[c] + shift[c]), float4-vectorized in place.
__global__ __launch_bounds__(256) void bn_apply_kernel(
    float* __restrict__ h, const float* __restrict__ scale,
    const float* __restrict__ shift)
{
    int idx = blockIdx.x * 256 + threadIdx.x;
    if (idx >= NN * 32) return;
    float4 v = reinterpret_cast<float4*>(h)[idx];
    int c0 = (idx & 31) * 4;
    v.x = fmaxf(v.x * scale[c0 + 0] + shift[c0 + 0], 0.f);
    v.y = fmaxf(v.y * scale[c0 + 1] + shift[c0 + 1], 0.f);
    v.z = fmaxf(v.z * scale[c0 + 2] + shift[c0 + 2], 0.f);
    v.w = fmaxf(v.w * scale[c0 + 3] + shift[c0 + 3], 0.f);
    reinterpret_cast<float4*>(h)[idx] = v;
}

// ---------------------------------------------------------------------------
// Global add pool over sorted graph ids: run-length accumulate, flush on
// id change -> few atomics per block.
// ---------------------------------------------------------------------------
#define POOL_CHUNK 250
__global__ __launch_bounds__(128) void pool_kernel(
    const float* __restrict__ h, const int* __restrict__ batch,
    float* __restrict__ g)
{
    int c = threadIdx.x;
    int r0 = blockIdx.x * POOL_CHUNK;
    int rend = min(r0 + POOL_CHUNK, NN);
    if (r0 >= rend) return;
    int cur = batch[r0];
    float acc = 0.f;
    for (int r = r0; r < rend; r++) {
        int gid = batch[r];
        if (gid != cur) {
            atomicAdd(&g[cur * HD + c], acc);
            acc = 0.f;
            cur = gid;
        }
        acc += h[(size_t)r * HD + c];
    }
    atomicAdd(&g[cur * HD + c], acc);
}

// y[r,:] = relu(g[r,:] @ Wf1 + bf1) ; one block per row.
__global__ __launch_bounds__(128) void final1_kernel(
    const float* __restrict__ g, const float* __restrict__ Wf1,
    const float* __restrict__ bf1, float* __restrict__ y)
{
    __shared__ float gr[HD];
    int r = blockIdx.x, c = threadIdx.x;
    gr[c] = g[r * HD + c];
    __syncthreads();
    float acc = bf1[c];
    for (int k = 0; k < HD; k++) acc += gr[k] * Wf1[k * HD + c];
    y[r * HD + c] = fmaxf(acc, 0.f);
}

// out[r,:] = y[r,:] @ Wf2 + bf2 ; one block per row.
__global__ __launch_bounds__(64) void final2_kernel(
    const float* __restrict__ y, const float* __restrict__ Wf2,
    const float* __restrict__ bf2, float* __restrict__ out)
{
    __shared__ float yr[HD];
    int r = blockIdx.x, c = threadIdx.x;
    yr[c] = y[r * HD + c];
    yr[c + 64] = y[r * HD + c + 64];
    __syncthreads();
    float acc = bf2[c];
    for (int k = 0; k < HD; k++) acc += yr[k] * Wf2[k * OUTF + c];
    out[r * OUTF + c] = acc;
}

// ---------------------------------------------------------------------------
extern "C" void kernel_launch(void* const* d_in, const int* in_sizes, int n_in,
                              void* d_out, int out_size, void* d_ws, size_t ws_size,
                              hipStream_t stream)
{
    const float* x     = (const float*)d_in[0];
    const int*   ei    = (const int*)  d_in[1];
    const int*   batch = (const int*)  d_in[2];
    const float* W1    = (const float*)d_in[3];
    const float* b1    = (const float*)d_in[4];
    const float* W2    = (const float*)d_in[5];
    const float* b2    = (const float*)d_in[6];
    const float* gamma = (const float*)d_in[7];
    const float* beta  = (const float*)d_in[8];
    const float* Wf1   = (const float*)d_in[9];
    const float* bf1   = (const float*)d_in[10];
    const float* Wf2   = (const float*)d_in[11];
    const float* bf2   = (const float*)d_in[12];
    float* out = (float*)d_out;

    float* ws   = (float*)d_ws;
    const size_t BIG = (size_t)NN * HD;       // 6.4M floats
    float* hbuf = ws;
    float* agg  = ws + BIG;
    float* mid  = ws + 2 * BIG;
    float* smal = ws + 3 * BIG;
    float* sums  = smal;
    float* sumsq = smal + 128;
    float* scale = smal + 256;
    float* shift = smal + 384;
    float* gpool = smal + 512;                // 128*128
    float* ymid  = gpool + NG * HD;           // 128*128

    const int* src = ei;
    const int* dst = ei + NE;

    const int gemm_grid = (NN + 31) / 32;     // 1563
    const int scat_grid = (NE * 32 + 255) / 256;  // 75000
    const int bn_grid   = (NN * 32 + 255) / 256;  // 6250

    for (int l = 0; l < NL; l++) {
        const float* hin = (l == 0) ? x : hbuf;
        hipMemsetAsync(agg, 0, BIG * sizeof(float), stream);
        hipMemsetAsync(sums, 0, 256 * sizeof(float), stream);
        scatter_kernel<<<scat_grid, 256, 0, stream>>>(hin, src, dst, agg);
        gemm128<true, true, false><<<gemm_grid, 256, 0, stream>>>(
            hin, agg, W1 + (size_t)l * HD * HD, b1 + l * HD, mid, nullptr, nullptr);
        gemm128<false, false, true><<<gemm_grid, 256, 0, stream>>>(
            mid, nullptr, W2 + (size_t)l * HD * HD, b2 + l * HD, hbuf, sums, sumsq);
        bn_finalize_kernel<<<1, 128, 0, stream>>>(sums, sumsq,
            gamma + l * HD, beta + l * HD, scale, shift);
        bn_apply_kernel<<<bn_grid, 256, 0, stream>>>(hbuf, scale, shift);
    }

    hipMemsetAsync(gpool, 0, (size_t)NG * HD * sizeof(float), stream);
    pool_kernel<<<(NN + POOL_CHUNK - 1) / POOL_CHUNK, 128, 0, stream>>>(hbuf, batch, gpool);
    final1_kernel<<<NG, 128, 0, stream>>>(gpool, Wf1, bf1, ymid);
    final2_kernel<<<NG, 64, 0, stream>>>(ymid, Wf2, bf2, out);
}

// Round 4
// 841.494 us; speedup vs baseline: 5.5441x; 5.5441x over previous
//
#include <hip/hip_runtime.h>

#define NN 50000
#define NE 600000
#define HD 128
#define OUTF 64
#define NL 4
#define NG 128
#define BN_EPS 1e-5f
#define NSB 196   // ceil(NN/256) scan blocks

// ---------------------------------------------------------------------------
// GEMM: C[NN,128] = act( (A (+Agg)) @ W + bias ), W is [128,128] row-major.
// Block: 256 threads, 32-row tile. LDS: W (64KB) + A-tile (16KB) = 80KB
// -> 2 blocks/CU. Each thread: 4 rows x 4 cols register tile.
// STATS: fused BatchNorm partial sums/sumsq (per-column) via LDS + atomics.
// ---------------------------------------------------------------------------
template<bool ADD_AGG, bool RELU, bool STATS>
__global__ __launch_bounds__(256) void gemm128(
    const float* __restrict__ A, const float* __restrict__ Agg,
    const float* __restrict__ W, const float* __restrict__ bias,
    float* __restrict__ C, float* __restrict__ sums, float* __restrict__ sumsq)
{
    __shared__ float Ws[HD * HD];
    __shared__ float As[32 * HD];
    const int t = threadIdx.x;
    const int row0 = blockIdx.x * 32;

    #pragma unroll 8
    for (int i = t; i < HD * HD; i += 256) Ws[i] = W[i];

    for (int i = t; i < 32 * HD; i += 256) {
        int r = row0 + (i >> 7);
        float v = 0.f;
        if (r < NN) {
            v = A[(size_t)r * HD + (i & 127)];
            if (ADD_AGG) v += Agg[(size_t)r * HD + (i & 127)];
        }
        As[i] = v;
    }
    __syncthreads();

    const int tc = t & 31;   // column group: cols tc*4 .. tc*4+3
    const int tr = t >> 5;   // row group:    rows tr*4 .. tr*4+3

    float acc[4][4];
    #pragma unroll
    for (int i = 0; i < 4; i++)
        #pragma unroll
        for (int j = 0; j < 4; j++) acc[i][j] = 0.f;

    const float4* WsV = reinterpret_cast<const float4*>(Ws);
    #pragma unroll 4
    for (int k = 0; k < HD; k++) {
        float4 w = WsV[k * 32 + tc];          // ds_read_b128, conflict-free
        #pragma unroll
        for (int i = 0; i < 4; i++) {
            float a = As[(tr * 4 + i) * HD + k];  // 2 distinct addrs/wave: free
            acc[i][0] += a * w.x;
            acc[i][1] += a * w.y;
            acc[i][2] += a * w.z;
            acc[i][3] += a * w.w;
        }
    }

    const float b0 = bias[tc * 4 + 0], b1 = bias[tc * 4 + 1];
    const float b2 = bias[tc * 4 + 2], b3 = bias[tc * 4 + 3];
    float vals[4][4];
    #pragma unroll
    for (int i = 0; i < 4; i++) {
        int r = row0 + tr * 4 + i;
        float4 v;
        v.x = acc[i][0] + b0; v.y = acc[i][1] + b1;
        v.z = acc[i][2] + b2; v.w = acc[i][3] + b3;
        if (RELU) {
            v.x = fmaxf(v.x, 0.f); v.y = fmaxf(v.y, 0.f);
            v.z = fmaxf(v.z, 0.f); v.w = fmaxf(v.w, 0.f);
        }
        vals[i][0] = v.x; vals[i][1] = v.y; vals[i][2] = v.z; vals[i][3] = v.w;
        if (r < NN)
            *reinterpret_cast<float4*>(&C[(size_t)r * HD + tc * 4]) = v;
    }

    if (STATS) {
        __syncthreads();   // everyone done reading As; reuse it for reduction
        float s[4] = {0, 0, 0, 0}, q[4] = {0, 0, 0, 0};
        #pragma unroll
        for (int i = 0; i < 4; i++) {
            int r = row0 + tr * 4 + i;
            if (r < NN) {
                #pragma unroll
                for (int j = 0; j < 4; j++) {
                    float v = vals[i][j];
                    s[j] += v; q[j] += v * v;
                }
            }
        }
        #pragma unroll
        for (int j = 0; j < 4; j++) {
            As[tr * HD + tc * 4 + j]          = s[j];
            As[8 * HD + tr * HD + tc * 4 + j] = q[j];
        }
        __syncthreads();
        if (t < HD) {
            float ss = 0.f, qq = 0.f;
            #pragma unroll
            for (int g = 0; g < 8; g++) {
                ss += As[g * HD + t];
                qq += As[8 * HD + g * HD + t];
            }
            atomicAdd(&sums[t], ss);
            atomicAdd(&sumsq[t], qq);
        }
    }
}

// ---------------------------------------------------------------------------
// CSR build: degree histogram -> 2-level exclusive scan -> slot fill.
// ---------------------------------------------------------------------------
__global__ __launch_bounds__(256) void deg_hist_kernel(
    const int* __restrict__ dst, int* __restrict__ deg)
{
    int e = blockIdx.x * 256 + threadIdx.x;
    if (e < NE) atomicAdd(&deg[dst[e]], 1);
}

__global__ __launch_bounds__(256) void scan_partial_kernel(
    const int* __restrict__ deg, int* __restrict__ bsum)
{
    __shared__ int sd[256];
    int t = threadIdx.x;
    int i = blockIdx.x * 256 + t;
    sd[t] = (i < NN) ? deg[i] : 0;
    __syncthreads();
    for (int o = 128; o > 0; o >>= 1) {
        if (t < o) sd[t] += sd[t + o];
        __syncthreads();
    }
    if (t == 0) bsum[blockIdx.x] = sd[0];
}

__global__ __launch_bounds__(256) void scan_bsums_kernel(
    const int* __restrict__ bsum, int* __restrict__ boff)
{
    __shared__ int sd[256];
    int t = threadIdx.x;
    int v = (t < NSB) ? bsum[t] : 0;
    sd[t] = v;
    __syncthreads();
    for (int o = 1; o < 256; o <<= 1) {
        int x = (t >= o) ? sd[t - o] : 0;
        __syncthreads();
        sd[t] += x;
        __syncthreads();
    }
    if (t < NSB) boff[t] = sd[t] - v;   // exclusive
}

__global__ __launch_bounds__(256) void scan_final_kernel(
    const int* __restrict__ deg, const int* __restrict__ boff,
    int* __restrict__ row_ptr, int* __restrict__ cursor)
{
    __shared__ int sd[256];
    int t = threadIdx.x;
    int i = blockIdx.x * 256 + t;
    int v = (i < NN) ? deg[i] : 0;
    sd[t] = v;
    __syncthreads();
    for (int o = 1; o < 256; o <<= 1) {
        int x = (t >= o) ? sd[t - o] : 0;
        __syncthreads();
        sd[t] += x;
        __syncthreads();
    }
    int excl = sd[t] - v + boff[blockIdx.x];
    if (i < NN) { row_ptr[i] = excl; cursor[i] = excl; }
    if (i == NN - 1) row_ptr[NN] = excl + v;   // == NE
}

__global__ __launch_bounds__(256) void fill_csr_kernel(
    const int* __restrict__ src, const int* __restrict__ dst,
    int* __restrict__ cursor, int* __restrict__ csr)
{
    int e = blockIdx.x * 256 + threadIdx.x;
    if (e >= NE) return;
    int p = atomicAdd(&cursor[dst[e]], 1);
    csr[p] = src[e];
}

// ---------------------------------------------------------------------------
// Gather aggregation: agg[n] = sum_{j in N(n)} h[j]. One 32-lane group per
// node, float4 per lane (512B coalesced per neighbor row), 4-deep unroll.
// ---------------------------------------------------------------------------
__global__ __launch_bounds__(256) void gather_kernel(
    const float* __restrict__ h, const int* __restrict__ row_ptr,
    const int* __restrict__ csr, float* __restrict__ agg)
{
    int n = blockIdx.x * 8 + (threadIdx.x >> 5);
    if (n >= NN) return;
    int c = (threadIdx.x & 31) * 4;
    int p = row_ptr[n], pe = row_ptr[n + 1];
    float4 acc = {0.f, 0.f, 0.f, 0.f};
    for (; p + 4 <= pe; p += 4) {
        int s0 = csr[p], s1 = csr[p + 1], s2 = csr[p + 2], s3 = csr[p + 3];
        float4 a = *reinterpret_cast<const float4*>(&h[(size_t)s0 * HD + c]);
        float4 b = *reinterpret_cast<const float4*>(&h[(size_t)s1 * HD + c]);
        float4 d = *reinterpret_cast<const float4*>(&h[(size_t)s2 * HD + c]);
        float4 e = *reinterpret_cast<const float4*>(&h[(size_t)s3 * HD + c]);
        acc.x += (a.x + b.x) + (d.x + e.x);
        acc.y += (a.y + b.y) + (d.y + e.y);
        acc.z += (a.z + b.z) + (d.z + e.z);
        acc.w += (a.w + b.w) + (d.w + e.w);
    }
    for (; p < pe; p++) {
        float4 a = *reinterpret_cast<const float4*>(&h[(size_t)csr[p] * HD + c]);
        acc.x += a.x; acc.y += a.y; acc.z += a.z; acc.w += a.w;
    }
    *reinterpret_cast<float4*>(&agg[(size_t)n * HD + c]) = acc;
}

// ---------------------------------------------------------------------------
// BN finalize: scale/shift from accumulated sums/sumsq (population variance).
// ---------------------------------------------------------------------------
__global__ void bn_finalize_kernel(
    const float* __restrict__ sums, const float* __restrict__ sumsq,
    const float* __restrict__ gamma, const float* __restrict__ beta,
    float* __restrict__ scale, float* __restrict__ shift)
{
    int c = threadIdx.x;
    const float invN = 1.f / (float)NN;
    float mean = sums[c] * invN;
    float var = sumsq[c] * invN - mean * mean;
    float inv = rsqrtf(var + BN_EPS);
    float sc = gamma[c] * inv;
    scale[c] = sc;
    shift[c] = beta[c] - mean * sc;
}

// h = relu(h * scale[c] + shift[c]), float4-vectorized in place.
__global__ __launch_bounds__(256) void bn_apply_kernel(
    float* __restrict__ h, const float* __restrict__ scale,
    const float* __restrict__ shift)
{
    int idx = blockIdx.x * 256 + threadIdx.x;
    if (idx >= NN * 32) return;
    float4 v = reinterpret_cast<float4*>(h)[idx];
    int c0 = (idx & 31) * 4;
    v.x = fmaxf(v.x * scale[c0 + 0] + shift[c0 + 0], 0.f);
    v.y = fmaxf(v.y * scale[c0 + 1] + shift[c0 + 1], 0.f);
    v.z = fmaxf(v.z * scale[c0 + 2] + shift[c0 + 2], 0.f);
    v.w = fmaxf(v.w * scale[c0 + 3] + shift[c0 + 3], 0.f);
    reinterpret_cast<float4*>(h)[idx] = v;
}

// ---------------------------------------------------------------------------
// Global add pool over sorted graph ids: run-length accumulate, flush on
// id change -> few atomics per block.
// ---------------------------------------------------------------------------
#define POOL_CHUNK 250
__global__ __launch_bounds__(128) void pool_kernel(
    const float* __restrict__ h, const int* __restrict__ batch,
    float* __restrict__ g)
{
    int c = threadIdx.x;
    int r0 = blockIdx.x * POOL_CHUNK;
    int rend = min(r0 + POOL_CHUNK, NN);
    if (r0 >= rend) return;
    int cur = batch[r0];
    float acc = 0.f;
    for (int r = r0; r < rend; r++) {
        int gid = batch[r];
        if (gid != cur) {
            atomicAdd(&g[cur * HD + c], acc);
            acc = 0.f;
            cur = gid;
        }
        acc += h[(size_t)r * HD + c];
    }
    atomicAdd(&g[cur * HD + c], acc);
}

// y[r,:] = relu(g[r,:] @ Wf1 + bf1) ; one block per row.
__global__ __launch_bounds__(128) void final1_kernel(
    const float* __restrict__ g, const float* __restrict__ Wf1,
    const float* __restrict__ bf1, float* __restrict__ y)
{
    __shared__ float gr[HD];
    int r = blockIdx.x, c = threadIdx.x;
    gr[c] = g[r * HD + c];
    __syncthreads();
    float acc = bf1[c];
    for (int k = 0; k < HD; k++) acc += gr[k] * Wf1[k * HD + c];
    y[r * HD + c] = fmaxf(acc, 0.f);
}

// out[r,:] = y[r,:] @ Wf2 + bf2 ; one block per row.
__global__ __launch_bounds__(64) void final2_kernel(
    const float* __restrict__ y, const float* __restrict__ Wf2,
    const float* __restrict__ bf2, float* __restrict__ out)
{
    __shared__ float yr[HD];
    int r = blockIdx.x, c = threadIdx.x;
    yr[c] = y[r * HD + c];
    yr[c + 64] = y[r * HD + c + 64];
    __syncthreads();
    float acc = bf2[c];
    for (int k = 0; k < HD; k++) acc += yr[k] * Wf2[k * OUTF + c];
    out[r * OUTF + c] = acc;
}

// ---------------------------------------------------------------------------
extern "C" void kernel_launch(void* const* d_in, const int* in_sizes, int n_in,
                              void* d_out, int out_size, void* d_ws, size_t ws_size,
                              hipStream_t stream)
{
    const float* x     = (const float*)d_in[0];
    const int*   ei    = (const int*)  d_in[1];
    const int*   batch = (const int*)  d_in[2];
    const float* W1    = (const float*)d_in[3];
    const float* b1    = (const float*)d_in[4];
    const float* W2    = (const float*)d_in[5];
    const float* b2    = (const float*)d_in[6];
    const float* gamma = (const float*)d_in[7];
    const float* beta  = (const float*)d_in[8];
    const float* Wf1   = (const float*)d_in[9];
    const float* bf1   = (const float*)d_in[10];
    const float* Wf2   = (const float*)d_in[11];
    const float* bf2   = (const float*)d_in[12];
    float* out = (float*)d_out;

    float* ws   = (float*)d_ws;
    const size_t BIG = (size_t)NN * HD;       // 6.4M floats
    float* hbuf = ws;
    float* agg  = ws + BIG;
    float* mid  = ws + 2 * BIG;
    float* smal = ws + 3 * BIG;
    float* sums  = smal;
    float* sumsq = smal + 128;
    float* scale = smal + 256;
    float* shift = smal + 384;
    float* gpool = smal + 512;                // 128*128
    float* ymid  = gpool + NG * HD;           // 128*128
    // int region for CSR (after 64K-float small region)
    int* ip      = (int*)(smal + 65536);
    int* deg     = ip;                        // NN
    int* row_ptr = ip + NN;                   // NN+1
    int* cursor  = row_ptr + NN + 1;          // NN
    int* bsum    = cursor + NN;               // 256
    int* boff    = bsum + 256;                // 256
    int* csr     = boff + 256;                // NE

    const int* src = ei;
    const int* dst = ei + NE;

    const int gemm_grid = (NN + 31) / 32;         // 1563
    const int bn_grid   = (NN * 32 + 255) / 256;  // 6250
    const int edge_grid = (NE + 255) / 256;       // 2344
    const int gath_grid = (NN + 7) / 8;           // 6250

    // ---- CSR build (per launch; deterministic work) ----
    hipMemsetAsync(deg, 0, NN * sizeof(int), stream);
    deg_hist_kernel<<<edge_grid, 256, 0, stream>>>(dst, deg);
    scan_partial_kernel<<<NSB, 256, 0, stream>>>(deg, bsum);
    scan_bsums_kernel<<<1, 256, 0, stream>>>(bsum, boff);
    scan_final_kernel<<<NSB, 256, 0, stream>>>(deg, boff, row_ptr, cursor);
    fill_csr_kernel<<<edge_grid, 256, 0, stream>>>(src, dst, cursor, csr);

    for (int l = 0; l < NL; l++) {
        const float* hin = (l == 0) ? x : hbuf;
        hipMemsetAsync(sums, 0, 256 * sizeof(float), stream);
        gather_kernel<<<gath_grid, 256, 0, stream>>>(hin, row_ptr, csr, agg);
        gemm128<true, true, false><<<gemm_grid, 256, 0, stream>>>(
            hin, agg, W1 + (size_t)l * HD * HD, b1 + l * HD, mid, nullptr, nullptr);
        gemm128<false, false, true><<<gemm_grid, 256, 0, stream>>>(
            mid, nullptr, W2 + (size_t)l * HD * HD, b2 + l * HD, hbuf, sums, sumsq);
        bn_finalize_kernel<<<1, 128, 0, stream>>>(sums, sumsq,
            gamma + l * HD, beta + l * HD, scale, shift);
        bn_apply_kernel<<<bn_grid, 256, 0, stream>>>(hbuf, scale, shift);
    }

    hipMemsetAsync(gpool, 0, (size_t)NG * HD * sizeof(float), stream);
    pool_kernel<<<(NN + POOL_CHUNK - 1) / POOL_CHUNK, 128, 0, stream>>>(hbuf, batch, gpool);
    final1_kernel<<<NG, 128, 0, stream>>>(gpool, Wf1, bf1, ymid);
    final2_kernel<<<NG, 64, 0, stream>>>(ymid, Wf2, bf2, out);
}

// Round 5
// 717.159 us; speedup vs baseline: 6.5053x; 1.1734x over previous
//
#include <hip/hip_runtime.h>

#define NN 50000
#define NE 600000
#define HD 128
#define OUTF 64
#define NL 4
#define NG 128
#define BN_EPS 1e-5f
#define NSB 196   // ceil(NN/256) scan blocks

// ---------------------------------------------------------------------------
// GEMM: C[NN,128] = act( (A (+Agg)) @ W + bias ), W is [128,128] row-major.
// v2: W read directly from global (L1/L2-resident, shared by all blocks);
// LDS holds only the 64x128 A-tile (32KB) -> 5 blocks/CU, 20 waves/CU.
// Each thread: 8 rows x 4 cols register tile (32 FMA per k per 8 LDS reads).
// STATS: fused BatchNorm partial sums/sumsq (per-column) via LDS + atomics.
// ---------------------------------------------------------------------------
template<bool ADD_AGG, bool RELU, bool STATS>
__global__ __launch_bounds__(256) void gemm128(
    const float* __restrict__ A, const float* __restrict__ Agg,
    const float* __restrict__ W, const float* __restrict__ bias,
    float* __restrict__ C, float* __restrict__ sums, float* __restrict__ sumsq)
{
    __shared__ float As[64 * HD];   // 32 KB
    const int t = threadIdx.x;
    const int row0 = blockIdx.x * 64;

    // ---- stage A (+Agg) tile: 64 rows x 128 cols ----
    {
        const int r_off = t >> 5;        // 0..7
        const int c4 = (t & 31) * 4;
        #pragma unroll
        for (int rr = 0; rr < 8; rr++) {
            int lr = rr * 8 + r_off;
            int r = row0 + lr;
            float4 v = {0.f, 0.f, 0.f, 0.f};
            if (r < NN) {
                v = *reinterpret_cast<const float4*>(&A[(size_t)r * HD + c4]);
                if (ADD_AGG) {
                    float4 g = *reinterpret_cast<const float4*>(&Agg[(size_t)r * HD + c4]);
                    v.x += g.x; v.y += g.y; v.z += g.z; v.w += g.w;
                }
            }
            *reinterpret_cast<float4*>(&As[lr * HD + c4]) = v;
        }
    }
    __syncthreads();

    const int tc = t & 31;    // cols tc*4 .. tc*4+3
    const int tr = t >> 5;    // rows tr*8 .. tr*8+7 (local)

    float acc[8][4];
    #pragma unroll
    for (int i = 0; i < 8; i++)
        #pragma unroll
        for (int j = 0; j < 4; j++) acc[i][j] = 0.f;

    #pragma unroll 8
    for (int k = 0; k < HD; k++) {
        const float4 w = *reinterpret_cast<const float4*>(&W[k * HD + tc * 4]);
        #pragma unroll
        for (int i = 0; i < 8; i++) {
            float a = As[(tr * 8 + i) * HD + k];   // 2 distinct addrs/wave: free
            acc[i][0] += a * w.x;
            acc[i][1] += a * w.y;
            acc[i][2] += a * w.z;
            acc[i][3] += a * w.w;
        }
    }

    const float b0 = bias[tc * 4 + 0], b1 = bias[tc * 4 + 1];
    const float b2 = bias[tc * 4 + 2], b3 = bias[tc * 4 + 3];
    float vals[8][4];
    #pragma unroll
    for (int i = 0; i < 8; i++) {
        int r = row0 + tr * 8 + i;
        float4 v;
        v.x = acc[i][0] + b0; v.y = acc[i][1] + b1;
        v.z = acc[i][2] + b2; v.w = acc[i][3] + b3;
        if (RELU) {
            v.x = fmaxf(v.x, 0.f); v.y = fmaxf(v.y, 0.f);
            v.z = fmaxf(v.z, 0.f); v.w = fmaxf(v.w, 0.f);
        }
        vals[i][0] = v.x; vals[i][1] = v.y; vals[i][2] = v.z; vals[i][3] = v.w;
        if (r < NN)
            *reinterpret_cast<float4*>(&C[(size_t)r * HD + tc * 4]) = v;
    }

    if (STATS) {
        __syncthreads();   // all As reads done; reuse As for the reduction
        float s[4] = {0, 0, 0, 0}, q[4] = {0, 0, 0, 0};
        #pragma unroll
        for (int i = 0; i < 8; i++) {
            int r = row0 + tr * 8 + i;
            if (r < NN) {
                #pragma unroll
                for (int j = 0; j < 4; j++) {
                    float v = vals[i][j];
                    s[j] += v; q[j] += v * v;
                }
            }
        }
        #pragma unroll
        for (int j = 0; j < 4; j++) {
            As[tr * HD + tc * 4 + j]          = s[j];
            As[(8 + tr) * HD + tc * 4 + j]    = q[j];
        }
        __syncthreads();
        if (t < HD) {
            float ss = 0.f, qq = 0.f;
            #pragma unroll
            for (int g = 0; g < 8; g++) {
                ss += As[g * HD + t];
                qq += As[(8 + g) * HD + t];
            }
            atomicAdd(&sums[t], ss);
            atomicAdd(&sumsq[t], qq);
        }
    }
}

// ---------------------------------------------------------------------------
// CSR build: degree histogram -> 2-level exclusive scan -> slot fill.
// ---------------------------------------------------------------------------
__global__ __launch_bounds__(256) void deg_hist_kernel(
    const int* __restrict__ dst, int* __restrict__ deg)
{
    int e = blockIdx.x * 256 + threadIdx.x;
    if (e < NE) atomicAdd(&deg[dst[e]], 1);
}

__global__ __launch_bounds__(256) void scan_partial_kernel(
    const int* __restrict__ deg, int* __restrict__ bsum)
{
    __shared__ int sd[256];
    int t = threadIdx.x;
    int i = blockIdx.x * 256 + t;
    sd[t] = (i < NN) ? deg[i] : 0;
    __syncthreads();
    for (int o = 128; o > 0; o >>= 1) {
        if (t < o) sd[t] += sd[t + o];
        __syncthreads();
    }
    if (t == 0) bsum[blockIdx.x] = sd[0];
}

__global__ __launch_bounds__(256) void scan_bsums_kernel(
    const int* __restrict__ bsum, int* __restrict__ boff)
{
    __shared__ int sd[256];
    int t = threadIdx.x;
    int v = (t < NSB) ? bsum[t] : 0;
    sd[t] = v;
    __syncthreads();
    for (int o = 1; o < 256; o <<= 1) {
        int x = (t >= o) ? sd[t - o] : 0;
        __syncthreads();
        sd[t] += x;
        __syncthreads();
    }
    if (t < NSB) boff[t] = sd[t] - v;   // exclusive
}

__global__ __launch_bounds__(256) void scan_final_kernel(
    const int* __restrict__ deg, const int* __restrict__ boff,
    int* __restrict__ row_ptr, int* __restrict__ cursor)
{
    __shared__ int sd[256];
    int t = threadIdx.x;
    int i = blockIdx.x * 256 + t;
    int v = (i < NN) ? deg[i] : 0;
    sd[t] = v;
    __syncthreads();
    for (int o = 1; o < 256; o <<= 1) {
        int x = (t >= o) ? sd[t - o] : 0;
        __syncthreads();
        sd[t] += x;
        __syncthreads();
    }
    int excl = sd[t] - v + boff[blockIdx.x];
    if (i < NN) { row_ptr[i] = excl; cursor[i] = excl; }
    if (i == NN - 1) row_ptr[NN] = excl + v;   // == NE
}

__global__ __launch_bounds__(256) void fill_csr_kernel(
    const int* __restrict__ src, const int* __restrict__ dst,
    int* __restrict__ cursor, int* __restrict__ csr)
{
    int e = blockIdx.x * 256 + threadIdx.x;
    if (e >= NE) return;
    int p = atomicAdd(&cursor[dst[e]], 1);
    csr[p] = src[e];
}

// ---------------------------------------------------------------------------
// Gather aggregation: agg[n] = sum_{j in N(n)} h[j]. One 32-lane group per
// node, float4 per lane (512B coalesced per neighbor row), 4-deep unroll.
// ---------------------------------------------------------------------------
__global__ __launch_bounds__(256) void gather_kernel(
    const float* __restrict__ h, const int* __restrict__ row_ptr,
    const int* __restrict__ csr, float* __restrict__ agg)
{
    int n = blockIdx.x * 8 + (threadIdx.x >> 5);
    if (n >= NN) return;
    int c = (threadIdx.x & 31) * 4;
    int p = row_ptr[n], pe = row_ptr[n + 1];
    float4 acc = {0.f, 0.f, 0.f, 0.f};
    for (; p + 4 <= pe; p += 4) {
        int s0 = csr[p], s1 = csr[p + 1], s2 = csr[p + 2], s3 = csr[p + 3];
        float4 a = *reinterpret_cast<const float4*>(&h[(size_t)s0 * HD + c]);
        float4 b = *reinterpret_cast<const float4*>(&h[(size_t)s1 * HD + c]);
        float4 d = *reinterpret_cast<const float4*>(&h[(size_t)s2 * HD + c]);
        float4 e = *reinterpret_cast<const float4*>(&h[(size_t)s3 * HD + c]);
        acc.x += (a.x + b.x) + (d.x + e.x);
        acc.y += (a.y + b.y) + (d.y + e.y);
        acc.z += (a.z + b.z) + (d.z + e.z);
        acc.w += (a.w + b.w) + (d.w + e.w);
    }
    for (; p < pe; p++) {
        float4 a = *reinterpret_cast<const float4*>(&h[(size_t)csr[p] * HD + c]);
        acc.x += a.x; acc.y += a.y; acc.z += a.z; acc.w += a.w;
    }
    *reinterpret_cast<float4*>(&agg[(size_t)n * HD + c]) = acc;
}

// ---------------------------------------------------------------------------
// BN finalize: scale/shift from accumulated sums/sumsq (population variance).
// ---------------------------------------------------------------------------
__global__ void bn_finalize_kernel(
    const float* __restrict__ sums, const float* __restrict__ sumsq,
    const float* __restrict__ gamma, const float* __restrict__ beta,
    float* __restrict__ scale, float* __restrict__ shift)
{
    int c = threadIdx.x;
    const float invN = 1.f / (float)NN;
    float mean = sums[c] * invN;
    float var = sumsq[c] * invN - mean * mean;
    float inv = rsqrtf(var + BN_EPS);
    float sc = gamma[c] * inv;
    scale[c] = sc;
    shift[c] = beta[c] - mean * sc;
}

// h = relu(h * scale[c] + shift[c]), float4-vectorized in place.
__global__ __launch_bounds__(256) void bn_apply_kernel(
    float* __restrict__ h, const float* __restrict__ scale,
    const float* __restrict__ shift)
{
    int idx = blockIdx.x * 256 + threadIdx.x;
    if (idx >= NN * 32) return;
    float4 v = reinterpret_cast<float4*>(h)[idx];
    int c0 = (idx & 31) * 4;
    v.x = fmaxf(v.x * scale[c0 + 0] + shift[c0 + 0], 0.f);
    v.y = fmaxf(v.y * scale[c0 + 1] + shift[c0 + 1], 0.f);
    v.z = fmaxf(v.z * scale[c0 + 2] + shift[c0 + 2], 0.f);
    v.w = fmaxf(v.w * scale[c0 + 3] + shift[c0 + 3], 0.f);
    reinterpret_cast<float4*>(h)[idx] = v;
}

// ---------------------------------------------------------------------------
// Global add pool over sorted graph ids: run-length accumulate, flush on
// id change -> few atomics per block.
// ---------------------------------------------------------------------------
#define POOL_CHUNK 250
__global__ __launch_bounds__(128) void pool_kernel(
    const float* __restrict__ h, const int* __restrict__ batch,
    float* __restrict__ g)
{
    int c = threadIdx.x;
    int r0 = blockIdx.x * POOL_CHUNK;
    int rend = min(r0 + POOL_CHUNK, NN);
    if (r0 >= rend) return;
    int cur = batch[r0];
    float acc = 0.f;
    for (int r = r0; r < rend; r++) {
        int gid = batch[r];
        if (gid != cur) {
            atomicAdd(&g[cur * HD + c], acc);
            acc = 0.f;
            cur = gid;
        }
        acc += h[(size_t)r * HD + c];
    }
    atomicAdd(&g[cur * HD + c], acc);
}

// y[r,:] = relu(g[r,:] @ Wf1 + bf1) ; one block per row.
__global__ __launch_bounds__(128) void final1_kernel(
    const float* __restrict__ g, const float* __restrict__ Wf1,
    const float* __restrict__ bf1, float* __restrict__ y)
{
    __shared__ float gr[HD];
    int r = blockIdx.x, c = threadIdx.x;
    gr[c] = g[r * HD + c];
    __syncthreads();
    float acc = bf1[c];
    for (int k = 0; k < HD; k++) acc += gr[k] * Wf1[k * HD + c];
    y[r * HD + c] = fmaxf(acc, 0.f);
}

// out[r,:] = y[r,:] @ Wf2 + bf2 ; one block per row.
__global__ __launch_bounds__(64) void final2_kernel(
    const float* __restrict__ y, const float* __restrict__ Wf2,
    const float* __restrict__ bf2, float* __restrict__ out)
{
    __shared__ float yr[HD];
    int r = blockIdx.x, c = threadIdx.x;
    yr[c] = y[r * HD + c];
    yr[c + 64] = y[r * HD + c + 64];
    __syncthreads();
    float acc = bf2[c];
    for (int k = 0; k < HD; k++) acc += yr[k] * Wf2[k * OUTF + c];
    out[r * OUTF + c] = acc;
}

// ---------------------------------------------------------------------------
extern "C" void kernel_launch(void* const* d_in, const int* in_sizes, int n_in,
                              void* d_out, int out_size, void* d_ws, size_t ws_size,
                              hipStream_t stream)
{
    const float* x     = (const float*)d_in[0];
    const int*   ei    = (const int*)  d_in[1];
    const int*   batch = (const int*)  d_in[2];
    const float* W1    = (const float*)d_in[3];
    const float* b1    = (const float*)d_in[4];
    const float* W2    = (const float*)d_in[5];
    const float* b2    = (const float*)d_in[6];
    const float* gamma = (const float*)d_in[7];
    const float* beta  = (const float*)d_in[8];
    const float* Wf1   = (const float*)d_in[9];
    const float* bf1   = (const float*)d_in[10];
    const float* Wf2   = (const float*)d_in[11];
    const float* bf2   = (const float*)d_in[12];
    float* out = (float*)d_out;

    float* ws   = (float*)d_ws;
    const size_t BIG = (size_t)NN * HD;       // 6.4M floats
    float* hbuf = ws;
    float* agg  = ws + BIG;
    float* mid  = ws + 2 * BIG;
    float* smal = ws + 3 * BIG;
    float* sums  = smal;
    float* sumsq = smal + 128;
    float* scale = smal + 256;
    float* shift = smal + 384;
    float* gpool = smal + 512;                // 128*128
    float* ymid  = gpool + NG * HD;           // 128*128
    // int region for CSR (after 64K-float small region)
    int* ip      = (int*)(smal + 65536);
    int* deg     = ip;                        // NN
    int* row_ptr = ip + NN;                   // NN+1
    int* cursor  = row_ptr + NN + 1;          // NN
    int* bsum    = cursor + NN;               // 256
    int* boff    = bsum + 256;                // 256
    int* csr     = boff + 256;                // NE

    const int* src = ei;
    const int* dst = ei + NE;

    const int gemm_grid = (NN + 63) / 64;         // 782
    const int bn_grid   = (NN * 32 + 255) / 256;  // 6250
    const int edge_grid = (NE + 255) / 256;       // 2344
    const int gath_grid = (NN + 7) / 8;           // 6250

    // ---- CSR build (per launch; deterministic work) ----
    hipMemsetAsync(deg, 0, NN * sizeof(int), stream);
    deg_hist_kernel<<<edge_grid, 256, 0, stream>>>(dst, deg);
    scan_partial_kernel<<<NSB, 256, 0, stream>>>(deg, bsum);
    scan_bsums_kernel<<<1, 256, 0, stream>>>(bsum, boff);
    scan_final_kernel<<<NSB, 256, 0, stream>>>(deg, boff, row_ptr, cursor);
    fill_csr_kernel<<<edge_grid, 256, 0, stream>>>(src, dst, cursor, csr);

    for (int l = 0; l < NL; l++) {
        const float* hin = (l == 0) ? x : hbuf;
        hipMemsetAsync(sums, 0, 256 * sizeof(float), stream);
        gather_kernel<<<gath_grid, 256, 0, stream>>>(hin, row_ptr, csr, agg);
        gemm128<true, true, false><<<gemm_grid, 256, 0, stream>>>(
            hin, agg, W1 + (size_t)l * HD * HD, b1 + l * HD, mid, nullptr, nullptr);
        gemm128<false, false, true><<<gemm_grid, 256, 0, stream>>>(
            mid, nullptr, W2 + (size_t)l * HD * HD, b2 + l * HD, hbuf, sums, sumsq);
        bn_finalize_kernel<<<1, 128, 0, stream>>>(sums, sumsq,
            gamma + l * HD, beta + l * HD, scale, shift);
        bn_apply_kernel<<<bn_grid, 256, 0, stream>>>(hbuf, scale, shift);
    }

    hipMemsetAsync(gpool, 0, (size_t)NG * HD * sizeof(float), stream);
    pool_kernel<<<(NN + POOL_CHUNK - 1) / POOL_CHUNK, 128, 0, stream>>>(hbuf, batch, gpool);
    final1_kernel<<<NG, 128, 0, stream>>>(gpool, Wf1, bf1, ymid);
    final2_kernel<<<NG, 64, 0, stream>>>(ymid, Wf2, bf2, out);
}

// Round 6
// 531.197 us; speedup vs baseline: 8.7827x; 1.3501x over previous
//
#include <hip/hip_runtime.h>

#define NN 50000
#define NE 600000
#define HD 128
#define OUTF 64
#define NL 4
#define NG 128
#define BN_EPS 1e-5f
#define NSB 196   // ceil(NN/256) scan blocks

typedef __attribute__((ext_vector_type(8))) short short8v;
typedef __attribute__((ext_vector_type(4))) float float4v;

#define LDSW 136   // padded LDS row stride in bf16 elems (272B: +16B kills D=128 bank conflicts)

__device__ inline unsigned short f2bf(float f) {   // RNE f32->bf16 (finite inputs)
    unsigned int u = __float_as_uint(f);
    return (unsigned short)((u + 0x7FFF + ((u >> 16) & 1)) >> 16);
}

// ---------------------------------------------------------------------------
// W pre-pack: wpack[w][nt][kb][lane][i] = bf16( W[kb*32 + 8*(lane>>4) + i][nt*16 + (lane&15)] )
// w = layer*2 + {0:W1, 1:W2}. One-time, 16384 threads.
// ---------------------------------------------------------------------------
__global__ __launch_bounds__(256) void pack_w_kernel(
    const float* __restrict__ W1, const float* __restrict__ W2,
    short* __restrict__ wpack)
{
    int gid = blockIdx.x * 256 + threadIdx.x;    // 8*8*4*64 = 16384
    int l  = gid & 63;
    int kb = (gid >> 6) & 3;
    int nt = (gid >> 8) & 7;
    int w  = gid >> 11;                          // 0..7
    const float* W = (w & 1) ? (W2 + (size_t)(w >> 1) * HD * HD)
                             : (W1 + (size_t)(w >> 1) * HD * HD);
    int col  = nt * 16 + (l & 15);
    int krow = kb * 32 + (l >> 4) * 8;
    short* o = wpack + (size_t)w * 16384 + ((size_t)(nt * 4 + kb) * 64 + l) * 8;
    #pragma unroll
    for (int i = 0; i < 8; i++)
        o[i] = (short)f2bf(W[(size_t)(krow + i) * HD + col]);
}

// ---------------------------------------------------------------------------
// GEMM1 (MFMA): midb[r,:] = bf16( relu( (h[r,:]+agg[r,:]) @ W + bias ) )
// 64-row tile, 4 waves x 16 rows, per wave 8 n-tiles x 4 k-blk 16x16x32 MFMA.
// ---------------------------------------------------------------------------
__global__ __launch_bounds__(256) void gemm_mfma_a(
    const float* __restrict__ h, const float* __restrict__ agg,
    const short* __restrict__ wpackW, const float* __restrict__ bias,
    short* __restrict__ midb)
{
    __shared__ __align__(16) short As[64 * LDSW];
    const int t = threadIdx.x;
    const int row0 = blockIdx.x * 64;

    // stage A = bf16(h+agg): rows (t>>5) stride 8, cols (t&31)*4
    {
        const int c4 = (t & 31) * 4;
        const int rg = t >> 5;
        #pragma unroll
        for (int rr = 0; rr < 8; rr++) {
            int lr = rr * 8 + rg;
            int r = row0 + lr;
            float4 v = {0.f, 0.f, 0.f, 0.f};
            if (r < NN) {
                v = *reinterpret_cast<const float4*>(&h[(size_t)r * HD + c4]);
                float4 g = *reinterpret_cast<const float4*>(&agg[(size_t)r * HD + c4]);
                v.x += g.x; v.y += g.y; v.z += g.z; v.w += g.w;
            }
            *reinterpret_cast<short4*>(&As[lr * LDSW + c4]) = make_short4(
                (short)f2bf(v.x), (short)f2bf(v.y), (short)f2bf(v.z), (short)f2bf(v.w));
        }
    }
    __syncthreads();

    const int wv = t >> 6, l = t & 63;
    const int l16 = l & 15, lhi = l >> 4;
    const int wrow = wv * 16;

    short8v a[4];
    #pragma unroll
    for (int kb = 0; kb < 4; kb++)
        a[kb] = *reinterpret_cast<const short8v*>(&As[(wrow + l16) * LDSW + kb * 32 + lhi * 8]);

    float4v acc[8];
    #pragma unroll
    for (int nt = 0; nt < 8; nt++) acc[nt] = (float4v){0.f, 0.f, 0.f, 0.f};

    const short8v* wp = reinterpret_cast<const short8v*>(wpackW);
    #pragma unroll
    for (int nt = 0; nt < 8; nt++) {
        #pragma unroll
        for (int kb = 0; kb < 4; kb++) {
            short8v b = wp[(nt * 4 + kb) * 64 + l];
            acc[nt] = __builtin_amdgcn_mfma_f32_16x16x32_bf16(a[kb], b, acc[nt], 0, 0, 0);
        }
    }

    #pragma unroll
    for (int nt = 0; nt < 8; nt++) {
        float bnt = bias[nt * 16 + l16];
        #pragma unroll
        for (int j = 0; j < 4; j++) {
            int r = row0 + wrow + lhi * 4 + j;
            if (r < NN) {
                float v = fmaxf(acc[nt][j] + bnt, 0.f);
                midb[(size_t)r * HD + nt * 16 + l16] = (short)f2bf(v);
            }
        }
    }
}

// ---------------------------------------------------------------------------
// GEMM2 (MFMA): C[r,:] = f32( midb[r,:] @ W + bias ), fused BN sums/sumsq.
// ---------------------------------------------------------------------------
__global__ __launch_bounds__(256) void gemm_mfma_b(
    const short* __restrict__ midb, const short* __restrict__ wpackW,
    const float* __restrict__ bias, float* __restrict__ C,
    float* __restrict__ sums, float* __restrict__ sumsq)
{
    __shared__ __align__(16) short As[64 * LDSW];
    __shared__ float redS[4][HD];
    __shared__ float redQ[4][HD];
    const int t = threadIdx.x;
    const int row0 = blockIdx.x * 64;

    // stage bf16 tile: 16B per thread, rows (t>>4) stride 16
    {
        const int c8 = (t & 15) * 8;
        const int rg = t >> 4;
        #pragma unroll
        for (int rr = 0; rr < 4; rr++) {
            int lr = rr * 16 + rg;
            int r = row0 + lr;
            short8v v = (short8v){0,0,0,0,0,0,0,0};
            if (r < NN)
                v = *reinterpret_cast<const short8v*>(&midb[(size_t)r * HD + c8]);
            *reinterpret_cast<short8v*>(&As[lr * LDSW + c8]) = v;
        }
    }
    __syncthreads();

    const int wv = t >> 6, l = t & 63;
    const int l16 = l & 15, lhi = l >> 4;
    const int wrow = wv * 16;

    short8v a[4];
    #pragma unroll
    for (int kb = 0; kb < 4; kb++)
        a[kb] = *reinterpret_cast<const short8v*>(&As[(wrow + l16) * LDSW + kb * 32 + lhi * 8]);

    float4v acc[8];
    #pragma unroll
    for (int nt = 0; nt < 8; nt++) acc[nt] = (float4v){0.f, 0.f, 0.f, 0.f};

    const short8v* wp = reinterpret_cast<const short8v*>(wpackW);
    #pragma unroll
    for (int nt = 0; nt < 8; nt++) {
        #pragma unroll
        for (int kb = 0; kb < 4; kb++) {
            short8v b = wp[(nt * 4 + kb) * 64 + l];
            acc[nt] = __builtin_amdgcn_mfma_f32_16x16x32_bf16(a[kb], b, acc[nt], 0, 0, 0);
        }
    }

    #pragma unroll
    for (int nt = 0; nt < 8; nt++) {
        float bnt = bias[nt * 16 + l16];
        float snt = 0.f, qnt = 0.f;
        #pragma unroll
        for (int j = 0; j < 4; j++) {
            int r = row0 + wrow + lhi * 4 + j;
            if (r < NN) {
                float v = acc[nt][j] + bnt;
                C[(size_t)r * HD + nt * 16 + l16] = v;
                snt += v; qnt += v * v;
            }
        }
        snt += __shfl_xor(snt, 16); snt += __shfl_xor(snt, 32);
        qnt += __shfl_xor(qnt, 16); qnt += __shfl_xor(qnt, 32);
        if (lhi == 0) { redS[wv][nt * 16 + l16] = snt; redQ[wv][nt * 16 + l16] = qnt; }
    }
    __syncthreads();
    if (t < HD) {
        float ss = redS[0][t] + redS[1][t] + redS[2][t] + redS[3][t];
        float qq = redQ[0][t] + redQ[1][t] + redQ[2][t] + redQ[3][t];
        atomicAdd(&sums[t], ss);
        atomicAdd(&sumsq[t], qq);
    }
}

// ---------------------------------------------------------------------------
// CSR build: degree histogram -> 2-level exclusive scan -> slot fill.
// ---------------------------------------------------------------------------
__global__ __launch_bounds__(256) void deg_hist_kernel(
    const int* __restrict__ dst, int* __restrict__ deg)
{
    int e = blockIdx.x * 256 + threadIdx.x;
    if (e < NE) atomicAdd(&deg[dst[e]], 1);
}

__global__ __launch_bounds__(256) void scan_partial_kernel(
    const int* __restrict__ deg, int* __restrict__ bsum)
{
    __shared__ int sd[256];
    int t = threadIdx.x;
    int i = blockIdx.x * 256 + t;
    sd[t] = (i < NN) ? deg[i] : 0;
    __syncthreads();
    for (int o = 128; o > 0; o >>= 1) {
        if (t < o) sd[t] += sd[t + o];
        __syncthreads();
    }
    if (t == 0) bsum[blockIdx.x] = sd[0];
}

__global__ __launch_bounds__(256) void scan_bsums_kernel(
    const int* __restrict__ bsum, int* __restrict__ boff)
{
    __shared__ int sd[256];
    int t = threadIdx.x;
    int v = (t < NSB) ? bsum[t] : 0;
    sd[t] = v;
    __syncthreads();
    for (int o = 1; o < 256; o <<= 1) {
        int x = (t >= o) ? sd[t - o] : 0;
        __syncthreads();
        sd[t] += x;
        __syncthreads();
    }
    if (t < NSB) boff[t] = sd[t] - v;   // exclusive
}

__global__ __launch_bounds__(256) void scan_final_kernel(
    const int* __restrict__ deg, const int* __restrict__ boff,
    int* __restrict__ row_ptr, int* __restrict__ cursor)
{
    __shared__ int sd[256];
    int t = threadIdx.x;
    int i = blockIdx.x * 256 + t;
    int v = (i < NN) ? deg[i] : 0;
    sd[t] = v;
    __syncthreads();
    for (int o = 1; o < 256; o <<= 1) {
        int x = (t >= o) ? sd[t - o] : 0;
        __syncthreads();
        sd[t] += x;
        __syncthreads();
    }
    int excl = sd[t] - v + boff[blockIdx.x];
    if (i < NN) { row_ptr[i] = excl; cursor[i] = excl; }
    if (i == NN - 1) row_ptr[NN] = excl + v;   // == NE
}

__global__ __launch_bounds__(256) void fill_csr_kernel(
    const int* __restrict__ src, const int* __restrict__ dst,
    int* __restrict__ cursor, int* __restrict__ csr)
{
    int e = blockIdx.x * 256 + threadIdx.x;
    if (e >= NE) return;
    int p = atomicAdd(&cursor[dst[e]], 1);
    csr[p] = src[e];
}

// ---------------------------------------------------------------------------
// Gather aggregation: agg[n] = sum_{j in N(n)} h[j].
// ---------------------------------------------------------------------------
__global__ __launch_bounds__(256) void gather_kernel(
    const float* __restrict__ h, const int* __restrict__ row_ptr,
    const int* __restrict__ csr, float* __restrict__ agg)
{
    int n = blockIdx.x * 8 + (threadIdx.x >> 5);
    if (n >= NN) return;
    int c = (threadIdx.x & 31) * 4;
    int p = row_ptr[n], pe = row_ptr[n + 1];
    float4 acc = {0.f, 0.f, 0.f, 0.f};
    for (; p + 4 <= pe; p += 4) {
        int s0 = csr[p], s1 = csr[p + 1], s2 = csr[p + 2], s3 = csr[p + 3];
        float4 a = *reinterpret_cast<const float4*>(&h[(size_t)s0 * HD + c]);
        float4 b = *reinterpret_cast<const float4*>(&h[(size_t)s1 * HD + c]);
        float4 d = *reinterpret_cast<const float4*>(&h[(size_t)s2 * HD + c]);
        float4 e = *reinterpret_cast<const float4*>(&h[(size_t)s3 * HD + c]);
        acc.x += (a.x + b.x) + (d.x + e.x);
        acc.y += (a.y + b.y) + (d.y + e.y);
        acc.z += (a.z + b.z) + (d.z + e.z);
        acc.w += (a.w + b.w) + (d.w + e.w);
    }
    for (; p < pe; p++) {
        float4 a = *reinterpret_cast<const float4*>(&h[(size_t)csr[p] * HD + c]);
        acc.x += a.x; acc.y += a.y; acc.z += a.z; acc.w += a.w;
    }
    *reinterpret_cast<float4*>(&agg[(size_t)n * HD + c]) = acc;
}

// ---------------------------------------------------------------------------
// BN finalize + apply.
// ---------------------------------------------------------------------------
__global__ void bn_finalize_kernel(
    const float* __restrict__ sums, const float* __restrict__ sumsq,
    const float* __restrict__ gamma, const float* __restrict__ beta,
    float* __restrict__ scale, float* __restrict__ shift)
{
    int c = threadIdx.x;
    const float invN = 1.f / (float)NN;
    float mean = sums[c] * invN;
    float var = sumsq[c] * invN - mean * mean;
    float inv = rsqrtf(var + BN_EPS);
    float sc = gamma[c] * inv;
    scale[c] = sc;
    shift[c] = beta[c] - mean * sc;
}

__global__ __launch_bounds__(256) void bn_apply_kernel(
    float* __restrict__ h, const float* __restrict__ scale,
    const float* __restrict__ shift)
{
    int idx = blockIdx.x * 256 + threadIdx.x;
    if (idx >= NN * 32) return;
    float4 v = reinterpret_cast<float4*>(h)[idx];
    int c0 = (idx & 31) * 4;
    v.x = fmaxf(v.x * scale[c0 + 0] + shift[c0 + 0], 0.f);
    v.y = fmaxf(v.y * scale[c0 + 1] + shift[c0 + 1], 0.f);
    v.z = fmaxf(v.z * scale[c0 + 2] + shift[c0 + 2], 0.f);
    v.w = fmaxf(v.w * scale[c0 + 3] + shift[c0 + 3], 0.f);
    reinterpret_cast<float4*>(h)[idx] = v;
}

// ---------------------------------------------------------------------------
// Global add pool v2: 782 blocks x 8 groups x 8-row runs; run-length flush.
// ---------------------------------------------------------------------------
__global__ __launch_bounds__(256) void pool_kernel(
    const float* __restrict__ h, const int* __restrict__ batch,
    float* __restrict__ g)
{
    int grp = threadIdx.x >> 5;
    int lane = threadIdx.x & 31;
    int c = lane * 4;
    int r0 = blockIdx.x * 64 + grp * 8;
    if (r0 >= NN) return;
    int rend = min(r0 + 8, NN);
    int cur = batch[r0];
    float4 acc = {0.f, 0.f, 0.f, 0.f};
    for (int r = r0; r < rend; r++) {
        int id = batch[r];
        if (id != cur) {
            atomicAdd(&g[cur * HD + c + 0], acc.x);
            atomicAdd(&g[cur * HD + c + 1], acc.y);
            atomicAdd(&g[cur * HD + c + 2], acc.z);
            atomicAdd(&g[cur * HD + c + 3], acc.w);
            acc = {0.f, 0.f, 0.f, 0.f};
            cur = id;
        }
        float4 v = *reinterpret_cast<const float4*>(&h[(size_t)r * HD + c]);
        acc.x += v.x; acc.y += v.y; acc.z += v.z; acc.w += v.w;
    }
    atomicAdd(&g[cur * HD + c + 0], acc.x);
    atomicAdd(&g[cur * HD + c + 1], acc.y);
    atomicAdd(&g[cur * HD + c + 2], acc.z);
    atomicAdd(&g[cur * HD + c + 3], acc.w);
}

// y[r,:] = relu(g[r,:] @ Wf1 + bf1) ; one block per row.
__global__ __launch_bounds__(128) void final1_kernel(
    const float* __restrict__ g, const float* __restrict__ Wf1,
    const float* __restrict__ bf1, float* __restrict__ y)
{
    __shared__ float gr[HD];
    int r = blockIdx.x, c = threadIdx.x;
    gr[c] = g[r * HD + c];
    __syncthreads();
    float acc = bf1[c];
    for (int k = 0; k < HD; k++) acc += gr[k] * Wf1[k * HD + c];
    y[r * HD + c] = fmaxf(acc, 0.f);
}

// out[r,:] = y[r,:] @ Wf2 + bf2 ; one block per row.
__global__ __launch_bounds__(64) void final2_kernel(
    const float* __restrict__ y, const float* __restrict__ Wf2,
    const float* __restrict__ bf2, float* __restrict__ out)
{
    __shared__ float yr[HD];
    int r = blockIdx.x, c = threadIdx.x;
    yr[c] = y[r * HD + c];
    yr[c + 64] = y[r * HD + c + 64];
    __syncthreads();
    float acc = bf2[c];
    for (int k = 0; k < HD; k++) acc += yr[k] * Wf2[k * OUTF + c];
    out[r * OUTF + c] = acc;
}

// ---------------------------------------------------------------------------
extern "C" void kernel_launch(void* const* d_in, const int* in_sizes, int n_in,
                              void* d_out, int out_size, void* d_ws, size_t ws_size,
                              hipStream_t stream)
{
    const float* x     = (const float*)d_in[0];
    const int*   ei    = (const int*)  d_in[1];
    const int*   batch = (const int*)  d_in[2];
    const float* W1    = (const float*)d_in[3];
    const float* b1    = (const float*)d_in[4];
    const float* W2    = (const float*)d_in[5];
    const float* b2    = (const float*)d_in[6];
    const float* gamma = (const float*)d_in[7];
    const float* beta  = (const float*)d_in[8];
    const float* Wf1   = (const float*)d_in[9];
    const float* bf1   = (const float*)d_in[10];
    const float* Wf2   = (const float*)d_in[11];
    const float* bf2   = (const float*)d_in[12];
    float* out = (float*)d_out;

    float* ws   = (float*)d_ws;
    const size_t BIG = (size_t)NN * HD;       // 6.4M floats
    float* hbuf = ws;
    float* agg  = ws + BIG;
    short* midb = (short*)(ws + 2 * BIG);     // bf16 mid, NN x 128
    float* smal = ws + 3 * BIG;
    float* sums  = smal;
    float* sumsq = smal + 128;
    float* scale = smal + 256;
    float* shift = smal + 384;
    float* gpool = smal + 512;                // 128*128
    float* ymid  = gpool + NG * HD;           // 128*128
    // int region for CSR (after 64K-float small region)
    int* ip      = (int*)(smal + 65536);
    int* deg     = ip;                        // NN
    int* row_ptr = ip + NN;                   // NN+1
    int* cursor  = row_ptr + NN + 1;          // NN
    int* bsum    = cursor + NN;               // 256
    int* boff    = bsum + 256;                // 256
    int* csr     = boff + 256;                // NE
    short* wpack = (short*)(csr + NE);        // 8 * 16384 bf16

    const int* src = ei;
    const int* dst = ei + NE;

    const int gemm_grid = (NN + 63) / 64;         // 782
    const int bn_grid   = (NN * 32 + 255) / 256;  // 6250
    const int edge_grid = (NE + 255) / 256;       // 2344
    const int gath_grid = (NN + 7) / 8;           // 6250

    // ---- one-time per launch: W pre-pack + CSR build ----
    pack_w_kernel<<<64, 256, 0, stream>>>(W1, W2, wpack);
    hipMemsetAsync(deg, 0, NN * sizeof(int), stream);
    deg_hist_kernel<<<edge_grid, 256, 0, stream>>>(dst, deg);
    scan_partial_kernel<<<NSB, 256, 0, stream>>>(deg, bsum);
    scan_bsums_kernel<<<1, 256, 0, stream>>>(bsum, boff);
    scan_final_kernel<<<NSB, 256, 0, stream>>>(deg, boff, row_ptr, cursor);
    fill_csr_kernel<<<edge_grid, 256, 0, stream>>>(src, dst, cursor, csr);

    for (int l = 0; l < NL; l++) {
        const float* hin = (l == 0) ? x : hbuf;
        hipMemsetAsync(sums, 0, 256 * sizeof(float), stream);
        gather_kernel<<<gath_grid, 256, 0, stream>>>(hin, row_ptr, csr, agg);
        gemm_mfma_a<<<gemm_grid, 256, 0, stream>>>(
            hin, agg, wpack + (size_t)(l * 2 + 0) * 16384, b1 + l * HD, midb);
        gemm_mfma_b<<<gemm_grid, 256, 0, stream>>>(
            midb, wpack + (size_t)(l * 2 + 1) * 16384, b2 + l * HD, hbuf, sums, sumsq);
        bn_finalize_kernel<<<1, 128, 0, stream>>>(sums, sumsq,
            gamma + l * HD, beta + l * HD, scale, shift);
        bn_apply_kernel<<<bn_grid, 256, 0, stream>>>(hbuf, scale, shift);
    }

    hipMemsetAsync(gpool, 0, (size_t)NG * HD * sizeof(float), stream);
    pool_kernel<<<gemm_grid, 256, 0, stream>>>(hbuf, batch, gpool);
    final1_kernel<<<NG, 128, 0, stream>>>(gpool, Wf1, bf1, ymid);
    final2_kernel<<<NG, 64, 0, stream>>>(ymid, Wf2, bf2, out);
}

// Round 7
// 497.382 us; speedup vs baseline: 9.3798x; 1.0680x over previous
//
#include <hip/hip_runtime.h>

#define NN 50000
#define NE 600000
#define HD 128
#define OUTF 64
#define NL 4
#define NG 128
#define BN_EPS 1e-5f
#define NSB 196   // ceil(NN/256) scan blocks

typedef __attribute__((ext_vector_type(8))) short short8v;
typedef __attribute__((ext_vector_type(4))) float float4v;

#define LDSW 136   // padded LDS row stride in bf16 elems

__device__ inline unsigned short f2bf(float f) {   // RNE f32->bf16 (finite inputs)
    unsigned int u = __float_as_uint(f);
    return (unsigned short)((u + 0x7FFF + ((u >> 16) & 1)) >> 16);
}
__device__ inline float bf2f(short s) {
    return __uint_as_float(((unsigned int)(unsigned short)s) << 16);
}

// ---------------------------------------------------------------------------
// W pre-pack: wpack[w][nt][kb][lane][i] = bf16( W[kb*32 + 8*(lane>>4) + i][nt*16 + (lane&15)] )
// ---------------------------------------------------------------------------
__global__ __launch_bounds__(256) void pack_w_kernel(
    const float* __restrict__ W1, const float* __restrict__ W2,
    short* __restrict__ wpack)
{
    int gid = blockIdx.x * 256 + threadIdx.x;    // 8*8*4*64 = 16384
    int l  = gid & 63;
    int kb = (gid >> 6) & 3;
    int nt = (gid >> 8) & 7;
    int w  = gid >> 11;                          // 0..7
    const float* W = (w & 1) ? (W2 + (size_t)(w >> 1) * HD * HD)
                             : (W1 + (size_t)(w >> 1) * HD * HD);
    int col  = nt * 16 + (l & 15);
    int krow = kb * 32 + (l >> 4) * 8;
    short* o = wpack + (size_t)w * 16384 + ((size_t)(nt * 4 + kb) * 64 + l) * 8;
    #pragma unroll
    for (int i = 0; i < 8; i++)
        o[i] = (short)f2bf(W[(size_t)(krow + i) * HD + col]);
}

// x (f32) -> hb (bf16), one-time.
__global__ __launch_bounds__(256) void cvt_bf16_kernel(
    const float* __restrict__ x, short* __restrict__ hb)
{
    int idx = blockIdx.x * 256 + threadIdx.x;
    if (idx >= NN * 32) return;
    float4 v = reinterpret_cast<const float4*>(x)[idx];
    short4 o = make_short4((short)f2bf(v.x), (short)f2bf(v.y),
                           (short)f2bf(v.z), (short)f2bf(v.w));
    reinterpret_cast<short4*>(hb)[idx] = o;
}

// ---------------------------------------------------------------------------
// GEMM (MFMA): in bf16 [NN][128] @ W(+bias). 64-row tile, 4 waves.
// FIRST: out = bf16(relu(.)) -> outb.  else: out = f32 -> Cf, fused BN stats.
// ---------------------------------------------------------------------------
template<bool FIRST>
__global__ __launch_bounds__(256) void gemm_mfma(
    const short* __restrict__ inb, const short* __restrict__ wpackW,
    const float* __restrict__ bias, short* __restrict__ outb,
    float* __restrict__ Cf, float* __restrict__ sums, float* __restrict__ sumsq)
{
    __shared__ __align__(16) short As[64 * LDSW];
    __shared__ float redS[4][HD];
    __shared__ float redQ[4][HD];
    const int t = threadIdx.x;
    const int row0 = blockIdx.x * 64;

    // stage bf16 tile: 16B per thread, rows (t>>4) stride 16
    {
        const int c8 = (t & 15) * 8;
        const int rg = t >> 4;
        #pragma unroll
        for (int rr = 0; rr < 4; rr++) {
            int lr = rr * 16 + rg;
            int r = row0 + lr;
            short8v v = (short8v){0,0,0,0,0,0,0,0};
            if (r < NN)
                v = *reinterpret_cast<const short8v*>(&inb[(size_t)r * HD + c8]);
            *reinterpret_cast<short8v*>(&As[lr * LDSW + c8]) = v;
        }
    }
    __syncthreads();

    const int wv = t >> 6, l = t & 63;
    const int l16 = l & 15, lhi = l >> 4;
    const int wrow = wv * 16;

    short8v a[4];
    #pragma unroll
    for (int kb = 0; kb < 4; kb++)
        a[kb] = *reinterpret_cast<const short8v*>(&As[(wrow + l16) * LDSW + kb * 32 + lhi * 8]);

    float4v acc[8];
    #pragma unroll
    for (int nt = 0; nt < 8; nt++) acc[nt] = (float4v){0.f, 0.f, 0.f, 0.f};

    const short8v* wp = reinterpret_cast<const short8v*>(wpackW);
    #pragma unroll
    for (int nt = 0; nt < 8; nt++) {
        #pragma unroll
        for (int kb = 0; kb < 4; kb++) {
            short8v b = wp[(nt * 4 + kb) * 64 + l];
            acc[nt] = __builtin_amdgcn_mfma_f32_16x16x32_bf16(a[kb], b, acc[nt], 0, 0, 0);
        }
    }

    if (FIRST) {
        #pragma unroll
        for (int nt = 0; nt < 8; nt++) {
            float bnt = bias[nt * 16 + l16];
            #pragma unroll
            for (int j = 0; j < 4; j++) {
                int r = row0 + wrow + lhi * 4 + j;
                if (r < NN) {
                    float v = fmaxf(acc[nt][j] + bnt, 0.f);
                    outb[(size_t)r * HD + nt * 16 + l16] = (short)f2bf(v);
                }
            }
        }
    } else {
        #pragma unroll
        for (int nt = 0; nt < 8; nt++) {
            float bnt = bias[nt * 16 + l16];
            float snt = 0.f, qnt = 0.f;
            #pragma unroll
            for (int j = 0; j < 4; j++) {
                int r = row0 + wrow + lhi * 4 + j;
                if (r < NN) {
                    float v = acc[nt][j] + bnt;
                    Cf[(size_t)r * HD + nt * 16 + l16] = v;
                    snt += v; qnt += v * v;
                }
            }
            snt += __shfl_xor(snt, 16); snt += __shfl_xor(snt, 32);
            qnt += __shfl_xor(qnt, 16); qnt += __shfl_xor(qnt, 32);
            if (lhi == 0) { redS[wv][nt * 16 + l16] = snt; redQ[wv][nt * 16 + l16] = qnt; }
        }
        __syncthreads();
        if (t < HD) {
            float ss = redS[0][t] + redS[1][t] + redS[2][t] + redS[3][t];
            float qq = redQ[0][t] + redQ[1][t] + redQ[2][t] + redQ[3][t];
            atomicAdd(&sums[t], ss);
            atomicAdd(&sumsq[t], qq);
        }
    }
}

// ---------------------------------------------------------------------------
// CSR build: degree histogram -> 2-level exclusive scan -> slot fill.
// ---------------------------------------------------------------------------
__global__ __launch_bounds__(256) void deg_hist_kernel(
    const int* __restrict__ dst, int* __restrict__ deg)
{
    int e = blockIdx.x * 256 + threadIdx.x;
    if (e < NE) atomicAdd(&deg[dst[e]], 1);
}

__global__ __launch_bounds__(256) void scan_partial_kernel(
    const int* __restrict__ deg, int* __restrict__ bsum)
{
    __shared__ int sd[256];
    int t = threadIdx.x;
    int i = blockIdx.x * 256 + t;
    sd[t] = (i < NN) ? deg[i] : 0;
    __syncthreads();
    for (int o = 128; o > 0; o >>= 1) {
        if (t < o) sd[t] += sd[t + o];
        __syncthreads();
    }
    if (t == 0) bsum[blockIdx.x] = sd[0];
}

__global__ __launch_bounds__(256) void scan_bsums_kernel(
    const int* __restrict__ bsum, int* __restrict__ boff)
{
    __shared__ int sd[256];
    int t = threadIdx.x;
    int v = (t < NSB) ? bsum[t] : 0;
    sd[t] = v;
    __syncthreads();
    for (int o = 1; o < 256; o <<= 1) {
        int x = (t >= o) ? sd[t - o] : 0;
        __syncthreads();
        sd[t] += x;
        __syncthreads();
    }
    if (t < NSB) boff[t] = sd[t] - v;   // exclusive
}

__global__ __launch_bounds__(256) void scan_final_kernel(
    const int* __restrict__ deg, const int* __restrict__ boff,
    int* __restrict__ row_ptr, int* __restrict__ cursor)
{
    __shared__ int sd[256];
    int t = threadIdx.x;
    int i = blockIdx.x * 256 + t;
    int v = (i < NN) ? deg[i] : 0;
    sd[t] = v;
    __syncthreads();
    for (int o = 1; o < 256; o <<= 1) {
        int x = (t >= o) ? sd[t - o] : 0;
        __syncthreads();
        sd[t] += x;
        __syncthreads();
    }
    int excl = sd[t] - v + boff[blockIdx.x];
    if (i < NN) { row_ptr[i] = excl; cursor[i] = excl; }
    if (i == NN - 1) row_ptr[NN] = excl + v;   // == NE
}

__global__ __launch_bounds__(256) void fill_csr_kernel(
    const int* __restrict__ src, const int* __restrict__ dst,
    int* __restrict__ cursor, int* __restrict__ csr)
{
    int e = blockIdx.x * 256 + threadIdx.x;
    if (e >= NE) return;
    int p = atomicAdd(&cursor[dst[e]], 1);
    csr[p] = src[e];
}

// ---------------------------------------------------------------------------
// Gather (bf16): aggb[n] = bf16( hb[n] + sum_{j in N(n)} hb[j] ).
// 16 lanes per node (short8 = 16B per lane), f32 accumulate, 2-deep unroll.
// ---------------------------------------------------------------------------
__global__ __launch_bounds__(256) void gather_kernel_bf16(
    const short* __restrict__ hb, const int* __restrict__ row_ptr,
    const int* __restrict__ csr, short* __restrict__ aggb)
{
    int n = blockIdx.x * 16 + (threadIdx.x >> 4);
    if (n >= NN) return;
    int c = (threadIdx.x & 15) * 8;
    int p = row_ptr[n], pe = row_ptr[n + 1];

    float acc[8];
    {   // self term (GIN eps=0)
        short8v s = *reinterpret_cast<const short8v*>(&hb[(size_t)n * HD + c]);
        #pragma unroll
        for (int i = 0; i < 8; i++) acc[i] = bf2f(s[i]);
    }
    for (; p + 2 <= pe; p += 2) {
        int s0 = csr[p], s1 = csr[p + 1];
        short8v a = *reinterpret_cast<const short8v*>(&hb[(size_t)s0 * HD + c]);
        short8v b = *reinterpret_cast<const short8v*>(&hb[(size_t)s1 * HD + c]);
        #pragma unroll
        for (int i = 0; i < 8; i++) acc[i] += bf2f(a[i]) + bf2f(b[i]);
    }
    if (p < pe) {
        short8v a = *reinterpret_cast<const short8v*>(&hb[(size_t)csr[p] * HD + c]);
        #pragma unroll
        for (int i = 0; i < 8; i++) acc[i] += bf2f(a[i]);
    }
    short8v o;
    #pragma unroll
    for (int i = 0; i < 8; i++) o[i] = (short)f2bf(acc[i]);
    *reinterpret_cast<short8v*>(&aggb[(size_t)n * HD + c]) = o;
}

// ---------------------------------------------------------------------------
// BN finalize + apply (apply reads f32 C, writes bf16 hb, fused ReLU).
// ---------------------------------------------------------------------------
__global__ void bn_finalize_kernel(
    const float* __restrict__ sums, const float* __restrict__ sumsq,
    const float* __restrict__ gamma, const float* __restrict__ beta,
    float* __restrict__ scale, float* __restrict__ shift)
{
    int c = threadIdx.x;
    const float invN = 1.f / (float)NN;
    float mean = sums[c] * invN;
    float var = sumsq[c] * invN - mean * mean;
    float inv = rsqrtf(var + BN_EPS);
    float sc = gamma[c] * inv;
    scale[c] = sc;
    shift[c] = beta[c] - mean * sc;
}

__global__ __launch_bounds__(256) void bn_apply_kernel(
    const float* __restrict__ C, const float* __restrict__ scale,
    const float* __restrict__ shift, short* __restrict__ hb)
{
    int idx = blockIdx.x * 256 + threadIdx.x;
    if (idx >= NN * 32) return;
    float4 v = reinterpret_cast<const float4*>(C)[idx];
    int c0 = (idx & 31) * 4;
    v.x = fmaxf(v.x * scale[c0 + 0] + shift[c0 + 0], 0.f);
    v.y = fmaxf(v.y * scale[c0 + 1] + shift[c0 + 1], 0.f);
    v.z = fmaxf(v.z * scale[c0 + 2] + shift[c0 + 2], 0.f);
    v.w = fmaxf(v.w * scale[c0 + 3] + shift[c0 + 3], 0.f);
    short4 o = make_short4((short)f2bf(v.x), (short)f2bf(v.y),
                           (short)f2bf(v.z), (short)f2bf(v.w));
    reinterpret_cast<short4*>(hb)[idx] = o;
}

// ---------------------------------------------------------------------------
// Global add pool (bf16 input): 782 blocks x 16 groups x 4-row runs.
// ---------------------------------------------------------------------------
__global__ __launch_bounds__(256) void pool_kernel_bf16(
    const short* __restrict__ hb, const int* __restrict__ batch,
    float* __restrict__ g)
{
    int grp = threadIdx.x >> 4;       // 0..15
    int lane = threadIdx.x & 15;
    int c = lane * 8;
    int r0 = blockIdx.x * 64 + grp * 4;
    if (r0 >= NN) return;
    int rend = min(r0 + 4, NN);
    int cur = batch[r0];
    float acc[8] = {0, 0, 0, 0, 0, 0, 0, 0};
    for (int r = r0; r < rend; r++) {
        int id = batch[r];
        if (id != cur) {
            #pragma unroll
            for (int i = 0; i < 8; i++) {
                atomicAdd(&g[cur * HD + c + i], acc[i]);
                acc[i] = 0.f;
            }
            cur = id;
        }
        short8v v = *reinterpret_cast<const short8v*>(&hb[(size_t)r * HD + c]);
        #pragma unroll
        for (int i = 0; i < 8; i++) acc[i] += bf2f(v[i]);
    }
    #pragma unroll
    for (int i = 0; i < 8; i++)
        atomicAdd(&g[cur * HD + c + i], acc[i]);
}

// y[r,:] = relu(g[r,:] @ Wf1 + bf1) ; one block per row.
__global__ __launch_bounds__(128) void final1_kernel(
    const float* __restrict__ g, const float* __restrict__ Wf1,
    const float* __restrict__ bf1, float* __restrict__ y)
{
    __shared__ float gr[HD];
    int r = blockIdx.x, c = threadIdx.x;
    gr[c] = g[r * HD + c];
    __syncthreads();
    float acc = bf1[c];
    for (int k = 0; k < HD; k++) acc += gr[k] * Wf1[k * HD + c];
    y[r * HD + c] = fmaxf(acc, 0.f);
}

// out[r,:] = y[r,:] @ Wf2 + bf2 ; one block per row.
__global__ __launch_bounds__(64) void final2_kernel(
    const float* __restrict__ y, const float* __restrict__ Wf2,
    const float* __restrict__ bf2, float* __restrict__ out)
{
    __shared__ float yr[HD];
    int r = blockIdx.x, c = threadIdx.x;
    yr[c] = y[r * HD + c];
    yr[c + 64] = y[r * HD + c + 64];
    __syncthreads();
    float acc = bf2[c];
    for (int k = 0; k < HD; k++) acc += yr[k] * Wf2[k * OUTF + c];
    out[r * OUTF + c] = acc;
}

// ---------------------------------------------------------------------------
extern "C" void kernel_launch(void* const* d_in, const int* in_sizes, int n_in,
                              void* d_out, int out_size, void* d_ws, size_t ws_size,
                              hipStream_t stream)
{
    const float* x     = (const float*)d_in[0];
    const int*   ei    = (const int*)  d_in[1];
    const int*   batch = (const int*)  d_in[2];
    const float* W1    = (const float*)d_in[3];
    const float* b1    = (const float*)d_in[4];
    const float* W2    = (const float*)d_in[5];
    const float* b2    = (const float*)d_in[6];
    const float* gamma = (const float*)d_in[7];
    const float* beta  = (const float*)d_in[8];
    const float* Wf1   = (const float*)d_in[9];
    const float* bf1   = (const float*)d_in[10];
    const float* Wf2   = (const float*)d_in[11];
    const float* bf2   = (const float*)d_in[12];
    float* out = (float*)d_out;

    float* ws   = (float*)d_ws;
    const size_t BIG = (size_t)NN * HD;       // 6.4M elems
    float* Cbuf = ws;                         // f32 pre-BN C
    short* hb   = (short*)(ws + BIG);         // bf16 h   (BIG shorts)
    short* aggb = (short*)(ws + BIG) + BIG;   // bf16 agg (BIG shorts)
    short* midb = (short*)(ws + 2 * BIG);     // bf16 mid
    float* smal = ws + 3 * BIG;
    float* sums  = smal;
    float* sumsq = smal + 128;
    float* scale = smal + 256;
    float* shift = smal + 384;
    float* gpool = smal + 512;                // 128*128
    float* ymid  = gpool + NG * HD;           // 128*128
    int* ip      = (int*)(smal + 65536);
    int* deg     = ip;                        // NN
    int* row_ptr = ip + NN;                   // NN+1
    int* cursor  = row_ptr + NN + 1;          // NN
    int* bsum    = cursor + NN;               // 256
    int* boff    = bsum + 256;                // 256
    int* csr     = boff + 256;                // NE
    short* wpack = (short*)(csr + NE);        // 8 * 16384 bf16

    const int* src = ei;
    const int* dst = ei + NE;

    const int gemm_grid = (NN + 63) / 64;         // 782
    const int bn_grid   = (NN * 32 + 255) / 256;  // 6250
    const int edge_grid = (NE + 255) / 256;       // 2344
    const int gath_grid = (NN + 15) / 16;         // 3125

    // ---- one-time per launch: W pre-pack + x->bf16 + CSR build ----
    pack_w_kernel<<<64, 256, 0, stream>>>(W1, W2, wpack);
    cvt_bf16_kernel<<<bn_grid, 256, 0, stream>>>(x, hb);
    hipMemsetAsync(deg, 0, NN * sizeof(int), stream);
    deg_hist_kernel<<<edge_grid, 256, 0, stream>>>(dst, deg);
    scan_partial_kernel<<<NSB, 256, 0, stream>>>(deg, bsum);
    scan_bsums_kernel<<<1, 256, 0, stream>>>(bsum, boff);
    scan_final_kernel<<<NSB, 256, 0, stream>>>(deg, boff, row_ptr, cursor);
    fill_csr_kernel<<<edge_grid, 256, 0, stream>>>(src, dst, cursor, csr);

    for (int l = 0; l < NL; l++) {
        hipMemsetAsync(sums, 0, 256 * sizeof(float), stream);
        gather_kernel_bf16<<<gath_grid, 256, 0, stream>>>(hb, row_ptr, csr, aggb);
        gemm_mfma<true><<<gemm_grid, 256, 0, stream>>>(
            aggb, wpack + (size_t)(l * 2 + 0) * 16384, b1 + l * HD,
            midb, nullptr, nullptr, nullptr);
        gemm_mfma<false><<<gemm_grid, 256, 0, stream>>>(
            midb, wpack + (size_t)(l * 2 + 1) * 16384, b2 + l * HD,
            nullptr, Cbuf, sums, sumsq);
        bn_finalize_kernel<<<1, 128, 0, stream>>>(sums, sumsq,
            gamma + l * HD, beta + l * HD, scale, shift);
        bn_apply_kernel<<<bn_grid, 256, 0, stream>>>(Cbuf, scale, shift, hb);
    }

    hipMemsetAsync(gpool, 0, (size_t)NG * HD * sizeof(float), stream);
    pool_kernel_bf16<<<gemm_grid, 256, 0, stream>>>(hb, batch, gpool);
    final1_kernel<<<NG, 128, 0, stream>>>(gpool, Wf1, bf1, ymid);
    final2_kernel<<<NG, 64, 0, stream>>>(ymid, Wf2, bf2, out);
}

// Round 8
// 438.469 us; speedup vs baseline: 10.6401x; 1.1344x over previous
//
#include <hip/hip_runtime.h>

#define NN 50000
#define NE 600000
#define HD 128
#define OUTF 64
#define NL 4
#define NG 128
#define BN_EPS 1e-5f
#define NSB 196   // ceil(NN/256) scan blocks

typedef __attribute__((ext_vector_type(8))) short short8v;
typedef __attribute__((ext_vector_type(4))) float float4v;

#define LDSW 136   // padded LDS row stride in bf16 elems

__device__ inline unsigned short f2bf(float f) {   // RNE f32->bf16 (finite inputs)
    unsigned int u = __float_as_uint(f);
    return (unsigned short)((u + 0x7FFF + ((u >> 16) & 1)) >> 16);
}
__device__ inline float bf2f(short s) {
    return __uint_as_float(((unsigned int)(unsigned short)s) << 16);
}

// ---------------------------------------------------------------------------
// W pre-pack: wpack[w][nt][kb][lane][i] = bf16( W[kb*32 + 8*(lane>>4) + i][nt*16 + (lane&15)] )
// ---------------------------------------------------------------------------
__global__ __launch_bounds__(256) void pack_w_kernel(
    const float* __restrict__ W1, const float* __restrict__ W2,
    short* __restrict__ wpack)
{
    int gid = blockIdx.x * 256 + threadIdx.x;    // 8*8*4*64 = 16384
    int l  = gid & 63;
    int kb = (gid >> 6) & 3;
    int nt = (gid >> 8) & 7;
    int w  = gid >> 11;                          // 0..7
    const float* W = (w & 1) ? (W2 + (size_t)(w >> 1) * HD * HD)
                             : (W1 + (size_t)(w >> 1) * HD * HD);
    int col  = nt * 16 + (l & 15);
    int krow = kb * 32 + (l >> 4) * 8;
    short* o = wpack + (size_t)w * 16384 + ((size_t)(nt * 4 + kb) * 64 + l) * 8;
    #pragma unroll
    for (int i = 0; i < 8; i++)
        o[i] = (short)f2bf(W[(size_t)(krow + i) * HD + col]);
}

// x (f32) -> hb (bf16), one-time.
__global__ __launch_bounds__(256) void cvt_bf16_kernel(
    const float* __restrict__ x, short* __restrict__ hb)
{
    int idx = blockIdx.x * 256 + threadIdx.x;
    if (idx >= NN * 32) return;
    float4 v = reinterpret_cast<const float4*>(x)[idx];
    short4 o = make_short4((short)f2bf(v.x), (short)f2bf(v.y),
                           (short)f2bf(v.z), (short)f2bf(v.w));
    reinterpret_cast<short4*>(hb)[idx] = o;
}

// ---------------------------------------------------------------------------
// GEMM (MFMA): in bf16 [NN][128] @ W(+bias). 64-row tile, 4 waves.
// FIRST: out = bf16(relu(.)) -> outb.  else: out = f32 -> Cf, fused BN stats.
// ---------------------------------------------------------------------------
template<bool FIRST>
__global__ __launch_bounds__(256) void gemm_mfma(
    const short* __restrict__ inb, const short* __restrict__ wpackW,
    const float* __restrict__ bias, short* __restrict__ outb,
    float* __restrict__ Cf, float* __restrict__ sums, float* __restrict__ sumsq)
{
    __shared__ __align__(16) short As[64 * LDSW];
    __shared__ float redS[4][HD];
    __shared__ float redQ[4][HD];
    const int t = threadIdx.x;
    const int row0 = blockIdx.x * 64;

    // stage bf16 tile: 16B per thread, rows (t>>4) stride 16
    {
        const int c8 = (t & 15) * 8;
        const int rg = t >> 4;
        #pragma unroll
        for (int rr = 0; rr < 4; rr++) {
            int lr = rr * 16 + rg;
            int r = row0 + lr;
            short8v v = (short8v){0,0,0,0,0,0,0,0};
            if (r < NN)
                v = *reinterpret_cast<const short8v*>(&inb[(size_t)r * HD + c8]);
            *reinterpret_cast<short8v*>(&As[lr * LDSW + c8]) = v;
        }
    }
    __syncthreads();

    const int wv = t >> 6, l = t & 63;
    const int l16 = l & 15, lhi = l >> 4;
    const int wrow = wv * 16;

    short8v a[4];
    #pragma unroll
    for (int kb = 0; kb < 4; kb++)
        a[kb] = *reinterpret_cast<const short8v*>(&As[(wrow + l16) * LDSW + kb * 32 + lhi * 8]);

    float4v acc[8];
    #pragma unroll
    for (int nt = 0; nt < 8; nt++) acc[nt] = (float4v){0.f, 0.f, 0.f, 0.f};

    const short8v* wp = reinterpret_cast<const short8v*>(wpackW);
    #pragma unroll
    for (int nt = 0; nt < 8; nt++) {
        #pragma unroll
        for (int kb = 0; kb < 4; kb++) {
            short8v b = wp[(nt * 4 + kb) * 64 + l];
            acc[nt] = __builtin_amdgcn_mfma_f32_16x16x32_bf16(a[kb], b, acc[nt], 0, 0, 0);
        }
    }

    if (FIRST) {
        #pragma unroll
        for (int nt = 0; nt < 8; nt++) {
            float bnt = bias[nt * 16 + l16];
            #pragma unroll
            for (int j = 0; j < 4; j++) {
                int r = row0 + wrow + lhi * 4 + j;
                if (r < NN) {
                    float v = fmaxf(acc[nt][j] + bnt, 0.f);
                    outb[(size_t)r * HD + nt * 16 + l16] = (short)f2bf(v);
                }
            }
        }
    } else {
        #pragma unroll
        for (int nt = 0; nt < 8; nt++) {
            float bnt = bias[nt * 16 + l16];
            float snt = 0.f, qnt = 0.f;
            #pragma unroll
            for (int j = 0; j < 4; j++) {
                int r = row0 + wrow + lhi * 4 + j;
                if (r < NN) {
                    float v = acc[nt][j] + bnt;
                    Cf[(size_t)r * HD + nt * 16 + l16] = v;
                    snt += v; qnt += v * v;
                }
            }
            snt += __shfl_xor(snt, 16); snt += __shfl_xor(snt, 32);
            qnt += __shfl_xor(qnt, 16); qnt += __shfl_xor(qnt, 32);
            if (lhi == 0) { redS[wv][nt * 16 + l16] = snt; redQ[wv][nt * 16 + l16] = qnt; }
        }
        __syncthreads();
        if (t < HD) {
            float ss = redS[0][t] + redS[1][t] + redS[2][t] + redS[3][t];
            float qq = redQ[0][t] + redQ[1][t] + redQ[2][t] + redQ[3][t];
            atomicAdd(&sums[t], ss);
            atomicAdd(&sumsq[t], qq);
        }
    }
}

// ---------------------------------------------------------------------------
// CSR build: degree histogram -> 2-level exclusive scan -> slot fill.
// ---------------------------------------------------------------------------
__global__ __launch_bounds__(256) void deg_hist_kernel(
    const int* __restrict__ dst, int* __restrict__ deg)
{
    int e = blockIdx.x * 256 + threadIdx.x;
    if (e < NE) atomicAdd(&deg[dst[e]], 1);
}

__global__ __launch_bounds__(256) void scan_partial_kernel(
    const int* __restrict__ deg, int* __restrict__ bsum)
{
    __shared__ int sd[256];
    int t = threadIdx.x;
    int i = blockIdx.x * 256 + t;
    sd[t] = (i < NN) ? deg[i] : 0;
    __syncthreads();
    for (int o = 128; o > 0; o >>= 1) {
        if (t < o) sd[t] += sd[t + o];
        __syncthreads();
    }
    if (t == 0) bsum[blockIdx.x] = sd[0];
}

__global__ __launch_bounds__(256) void scan_bsums_kernel(
    const int* __restrict__ bsum, int* __restrict__ boff)
{
    __shared__ int sd[256];
    int t = threadIdx.x;
    int v = (t < NSB) ? bsum[t] : 0;
    sd[t] = v;
    __syncthreads();
    for (int o = 1; o < 256; o <<= 1) {
        int x = (t >= o) ? sd[t - o] : 0;
        __syncthreads();
        sd[t] += x;
        __syncthreads();
    }
    if (t < NSB) boff[t] = sd[t] - v;   // exclusive
}

__global__ __launch_bounds__(256) void scan_final_kernel(
    const int* __restrict__ deg, const int* __restrict__ boff,
    int* __restrict__ row_ptr, int* __restrict__ cursor)
{
    __shared__ int sd[256];
    int t = threadIdx.x;
    int i = blockIdx.x * 256 + t;
    int v = (i < NN) ? deg[i] : 0;
    sd[t] = v;
    __syncthreads();
    for (int o = 1; o < 256; o <<= 1) {
        int x = (t >= o) ? sd[t - o] : 0;
        __syncthreads();
        sd[t] += x;
        __syncthreads();
    }
    int excl = sd[t] - v + boff[blockIdx.x];
    if (i < NN) { row_ptr[i] = excl; cursor[i] = excl; }
    if (i == NN - 1) row_ptr[NN] = excl + v;   // == NE
}

__global__ __launch_bounds__(256) void fill_csr_kernel(
    const int* __restrict__ src, const int* __restrict__ dst,
    int* __restrict__ cursor, int* __restrict__ csr)
{
    int e = blockIdx.x * 256 + threadIdx.x;
    if (e >= NE) return;
    int p = atomicAdd(&cursor[dst[e]], 1);
    csr[p] = src[e];
}

// ---------------------------------------------------------------------------
// Gather (bf16): aggb[n] = bf16( hb[n] + sum_{j in N(n)} hb[j] ).
// 16 lanes per node (short8 = 16B per lane), f32 accumulate, 2-deep unroll.
// ---------------------------------------------------------------------------
__global__ __launch_bounds__(256) void gather_kernel_bf16(
    const short* __restrict__ hb, const int* __restrict__ row_ptr,
    const int* __restrict__ csr, short* __restrict__ aggb)
{
    int n = blockIdx.x * 16 + (threadIdx.x >> 4);
    if (n >= NN) return;
    int c = (threadIdx.x & 15) * 8;
    int p = row_ptr[n], pe = row_ptr[n + 1];

    float acc[8];
    {   // self term (GIN eps=0)
        short8v s = *reinterpret_cast<const short8v*>(&hb[(size_t)n * HD + c]);
        #pragma unroll
        for (int i = 0; i < 8; i++) acc[i] = bf2f(s[i]);
    }
    for (; p + 2 <= pe; p += 2) {
        int s0 = csr[p], s1 = csr[p + 1];
        short8v a = *reinterpret_cast<const short8v*>(&hb[(size_t)s0 * HD + c]);
        short8v b = *reinterpret_cast<const short8v*>(&hb[(size_t)s1 * HD + c]);
        #pragma unroll
        for (int i = 0; i < 8; i++) acc[i] += bf2f(a[i]) + bf2f(b[i]);
    }
    if (p < pe) {
        short8v a = *reinterpret_cast<const short8v*>(&hb[(size_t)csr[p] * HD + c]);
        #pragma unroll
        for (int i = 0; i < 8; i++) acc[i] += bf2f(a[i]);
    }
    short8v o;
    #pragma unroll
    for (int i = 0; i < 8; i++) o[i] = (short)f2bf(acc[i]);
    *reinterpret_cast<short8v*>(&aggb[(size_t)n * HD + c]) = o;
}

// ---------------------------------------------------------------------------
// BN apply v2: computes scale/shift in-block from sums/sumsq (no separate
// finalize dispatch), then relu((C - m)*inv*gamma + beta) -> bf16 hb.
// ---------------------------------------------------------------------------
__global__ __launch_bounds__(256) void bn_apply_kernel(
    const float* __restrict__ C, const float* __restrict__ sums,
    const float* __restrict__ sumsq, const float* __restrict__ gamma,
    const float* __restrict__ beta, short* __restrict__ hb)
{
    __shared__ float sscale[HD];
    __shared__ float sshift[HD];
    int t = threadIdx.x;
    if (t < HD) {
        const float invN = 1.f / (float)NN;
        float mean = sums[t] * invN;
        float var = sumsq[t] * invN - mean * mean;
        float inv = rsqrtf(var + BN_EPS);
        float sc = gamma[t] * inv;
        sscale[t] = sc;
        sshift[t] = beta[t] - mean * sc;
    }
    __syncthreads();
    int idx = blockIdx.x * 256 + t;
    if (idx >= NN * 32) return;
    float4 v = reinterpret_cast<const float4*>(C)[idx];
    int c0 = (idx & 31) * 4;
    v.x = fmaxf(v.x * sscale[c0 + 0] + sshift[c0 + 0], 0.f);
    v.y = fmaxf(v.y * sscale[c0 + 1] + sshift[c0 + 1], 0.f);
    v.z = fmaxf(v.z * sscale[c0 + 2] + sshift[c0 + 2], 0.f);
    v.w = fmaxf(v.w * sscale[c0 + 3] + sshift[c0 + 3], 0.f);
    short4 o = make_short4((short)f2bf(v.x), (short)f2bf(v.y),
                           (short)f2bf(v.z), (short)f2bf(v.w));
    reinterpret_cast<short4*>(hb)[idx] = o;
}

// ---------------------------------------------------------------------------
// Pool v3: one block per graph (batch sorted -> contiguous row range found
// by binary search). 16 row-groups x 16 col-groups, f32 reg accumulate,
// LDS reduce, direct store. ZERO atomics.
// ---------------------------------------------------------------------------
__global__ __launch_bounds__(256) void pool_kernel_v3(
    const short* __restrict__ hb, const int* __restrict__ batch,
    float* __restrict__ g)
{
    const int gr = blockIdx.x;
    int lo = 0, hi = NN;
    while (lo < hi) { int m = (lo + hi) >> 1; if (batch[m] < gr) lo = m + 1; else hi = m; }
    const int start = lo;
    hi = NN;
    while (lo < hi) { int m = (lo + hi) >> 1; if (batch[m] <= gr) lo = m + 1; else hi = m; }
    const int end = lo;

    const int cg = threadIdx.x & 15;   // col group: cols cg*8..cg*8+7
    const int rg = threadIdx.x >> 4;   // row group 0..15
    float acc[8] = {0, 0, 0, 0, 0, 0, 0, 0};
    for (int r = start + rg; r < end; r += 16) {
        short8v v = *reinterpret_cast<const short8v*>(&hb[(size_t)r * HD + cg * 8]);
        #pragma unroll
        for (int i = 0; i < 8; i++) acc[i] += bf2f(v[i]);
    }
    __shared__ float red[16][HD];
    #pragma unroll
    for (int i = 0; i < 8; i++) red[rg][cg * 8 + i] = acc[i];
    __syncthreads();
    if (threadIdx.x < HD) {
        float s = 0.f;
        #pragma unroll
        for (int k = 0; k < 16; k++) s += red[k][threadIdx.x];
        g[gr * HD + threadIdx.x] = s;
    }
}

// y[r,:] = relu(g[r,:] @ Wf1 + bf1) ; one block per row.
__global__ __launch_bounds__(128) void final1_kernel(
    const float* __restrict__ g, const float* __restrict__ Wf1,
    const float* __restrict__ bf1, float* __restrict__ y)
{
    __shared__ float gr[HD];
    int r = blockIdx.x, c = threadIdx.x;
    gr[c] = g[r * HD + c];
    __syncthreads();
    float acc = bf1[c];
    for (int k = 0; k < HD; k++) acc += gr[k] * Wf1[k * HD + c];
    y[r * HD + c] = fmaxf(acc, 0.f);
}

// out[r,:] = y[r,:] @ Wf2 + bf2 ; one block per row.
__global__ __launch_bounds__(64) void final2_kernel(
    const float* __restrict__ y, const float* __restrict__ Wf2,
    const float* __restrict__ bf2, float* __restrict__ out)
{
    __shared__ float yr[HD];
    int r = blockIdx.x, c = threadIdx.x;
    yr[c] = y[r * HD + c];
    yr[c + 64] = y[r * HD + c + 64];
    __syncthreads();
    float acc = bf2[c];
    for (int k = 0; k < HD; k++) acc += yr[k] * Wf2[k * OUTF + c];
    out[r * OUTF + c] = acc;
}

// ---------------------------------------------------------------------------
extern "C" void kernel_launch(void* const* d_in, const int* in_sizes, int n_in,
                              void* d_out, int out_size, void* d_ws, size_t ws_size,
                              hipStream_t stream)
{
    const float* x     = (const float*)d_in[0];
    const int*   ei    = (const int*)  d_in[1];
    const int*   batch = (const int*)  d_in[2];
    const float* W1    = (const float*)d_in[3];
    const float* b1    = (const float*)d_in[4];
    const float* W2    = (const float*)d_in[5];
    const float* b2    = (const float*)d_in[6];
    const float* gamma = (const float*)d_in[7];
    const float* beta  = (const float*)d_in[8];
    const float* Wf1   = (const float*)d_in[9];
    const float* bf1   = (const float*)d_in[10];
    const float* Wf2   = (const float*)d_in[11];
    const float* bf2   = (const float*)d_in[12];
    float* out = (float*)d_out;

    float* ws   = (float*)d_ws;
    const size_t BIG = (size_t)NN * HD;       // 6.4M elems
    float* Cbuf = ws;                         // f32 pre-BN C
    short* hb   = (short*)(ws + BIG);         // bf16 h   (BIG shorts)
    short* aggb = (short*)(ws + BIG) + BIG;   // bf16 agg (BIG shorts)
    short* midb = (short*)(ws + 2 * BIG);     // bf16 mid
    float* smal = ws + 3 * BIG;
    float* sums  = smal;
    float* sumsq = smal + 128;
    float* gpool = smal + 512;                // 128*128
    float* ymid  = gpool + NG * HD;           // 128*128
    int* ip      = (int*)(smal + 65536);
    int* deg     = ip;                        // NN
    int* row_ptr = ip + NN;                   // NN+1
    int* cursor  = row_ptr + NN + 1;          // NN
    int* bsum    = cursor + NN;               // 256
    int* boff    = bsum + 256;                // 256
    int* csr     = boff + 256;                // NE
    short* wpack = (short*)(csr + NE);        // 8 * 16384 bf16

    const int* src = ei;
    const int* dst = ei + NE;

    const int gemm_grid = (NN + 63) / 64;         // 782
    const int bn_grid   = (NN * 32 + 255) / 256;  // 6250
    const int edge_grid = (NE + 255) / 256;       // 2344
    const int gath_grid = (NN + 15) / 16;         // 3125

    // ---- one-time per launch: W pre-pack + x->bf16 + CSR build ----
    pack_w_kernel<<<64, 256, 0, stream>>>(W1, W2, wpack);
    cvt_bf16_kernel<<<bn_grid, 256, 0, stream>>>(x, hb);
    hipMemsetAsync(deg, 0, NN * sizeof(int), stream);
    deg_hist_kernel<<<edge_grid, 256, 0, stream>>>(dst, deg);
    scan_partial_kernel<<<NSB, 256, 0, stream>>>(deg, bsum);
    scan_bsums_kernel<<<1, 256, 0, stream>>>(bsum, boff);
    scan_final_kernel<<<NSB, 256, 0, stream>>>(deg, boff, row_ptr, cursor);
    fill_csr_kernel<<<edge_grid, 256, 0, stream>>>(src, dst, cursor, csr);

    for (int l = 0; l < NL; l++) {
        hipMemsetAsync(sums, 0, 256 * sizeof(float), stream);
        gather_kernel_bf16<<<gath_grid, 256, 0, stream>>>(hb, row_ptr, csr, aggb);
        gemm_mfma<true><<<gemm_grid, 256, 0, stream>>>(
            aggb, wpack + (size_t)(l * 2 + 0) * 16384, b1 + l * HD,
            midb, nullptr, nullptr, nullptr);
        gemm_mfma<false><<<gemm_grid, 256, 0, stream>>>(
            midb, wpack + (size_t)(l * 2 + 1) * 16384, b2 + l * HD,
            nullptr, Cbuf, sums, sumsq);
        bn_apply_kernel<<<bn_grid, 256, 0, stream>>>(
            Cbuf, sums, sumsq, gamma + l * HD, beta + l * HD, hb);
    }

    pool_kernel_v3<<<NG, 256, 0, stream>>>(hb, batch, gpool);
    final1_kernel<<<NG, 128, 0, stream>>>(gpool, Wf1, bf1, ymid);
    final2_kernel<<<NG, 64, 0, stream>>>(ymid, Wf2, bf2, out);
}

// Round 9
// 436.608 us; speedup vs baseline: 10.6854x; 1.0043x over previous
//
#include <hip/hip_runtime.h>

#define NN 50000
#define NE 600000
#define HD 128
#define OUTF 64
#define NL 4
#define NG 128
#define BN_EPS 1e-5f
#define NSB 196   // ceil(NN/256) scan blocks

typedef __attribute__((ext_vector_type(8))) short short8v;
typedef __attribute__((ext_vector_type(4))) float float4v;

#define LDSW 136   // padded LDS row stride in bf16 elems

__device__ inline unsigned short f2bf(float f) {   // RNE f32->bf16 (finite inputs)
    unsigned int u = __float_as_uint(f);
    return (unsigned short)((u + 0x7FFF + ((u >> 16) & 1)) >> 16);
}
__device__ inline float bf2f(short s) {
    return __uint_as_float(((unsigned int)(unsigned short)s) << 16);
}

// ---------------------------------------------------------------------------
// W pre-pack: wpack[w][nt][kb][lane][i] = bf16( W[kb*32 + 8*(lane>>4) + i][nt*16 + (lane&15)] )
// ---------------------------------------------------------------------------
__global__ __launch_bounds__(256) void pack_w_kernel(
    const float* __restrict__ W1, const float* __restrict__ W2,
    short* __restrict__ wpack)
{
    int gid = blockIdx.x * 256 + threadIdx.x;    // 8*8*4*64 = 16384
    int l  = gid & 63;
    int kb = (gid >> 6) & 3;
    int nt = (gid >> 8) & 7;
    int w  = gid >> 11;                          // 0..7
    const float* W = (w & 1) ? (W2 + (size_t)(w >> 1) * HD * HD)
                             : (W1 + (size_t)(w >> 1) * HD * HD);
    int col  = nt * 16 + (l & 15);
    int krow = kb * 32 + (l >> 4) * 8;
    short* o = wpack + (size_t)w * 16384 + ((size_t)(nt * 4 + kb) * 64 + l) * 8;
    #pragma unroll
    for (int i = 0; i < 8; i++)
        o[i] = (short)f2bf(W[(size_t)(krow + i) * HD + col]);
}

// x (f32) -> hb (bf16), one-time.
__global__ __launch_bounds__(256) void cvt_bf16_kernel(
    const float* __restrict__ x, short* __restrict__ hb)
{
    int idx = blockIdx.x * 256 + threadIdx.x;
    if (idx >= NN * 32) return;
    float4 v = reinterpret_cast<const float4*>(x)[idx];
    short4 o = make_short4((short)f2bf(v.x), (short)f2bf(v.y),
                           (short)f2bf(v.z), (short)f2bf(v.w));
    reinterpret_cast<short4*>(hb)[idx] = o;
}

// ---------------------------------------------------------------------------
// Fused gather + GEMM1 (MFMA):
//   As[lr] = bf16( hb[n] + sum_{j in N(n)} hb[j] )   (staged gather, f32 acc)
//   midb   = bf16( relu( As @ W1 + b1 ) )
// Also zeroes the BN stats buffers (block 0) for the following gemm_b.
// ---------------------------------------------------------------------------
__global__ __launch_bounds__(256) void gemm_ag_kernel(
    const short* __restrict__ hb, const int* __restrict__ row_ptr,
    const int* __restrict__ csr, const short* __restrict__ wpackW,
    const float* __restrict__ bias, short* __restrict__ midb,
    float* __restrict__ stats)   // sums(128)+sumsq(128) contiguous
{
    __shared__ __align__(16) short As[64 * LDSW];
    const int t = threadIdx.x;
    const int row0 = blockIdx.x * 64;

    if (blockIdx.x == 0 && t < 64)
        reinterpret_cast<float4*>(stats)[t] = (float4){0.f, 0.f, 0.f, 0.f};

    // ---- gather stage: 16 lanes per node, 16 nodes per iteration ----
    {
        const int ng = t >> 4;          // 0..15
        const int c8 = (t & 15) * 8;
        #pragma unroll
        for (int it = 0; it < 4; it++) {
            int lr = it * 16 + ng;
            int n = row0 + lr;
            float acc[8] = {0, 0, 0, 0, 0, 0, 0, 0};
            if (n < NN) {
                short8v s = *reinterpret_cast<const short8v*>(&hb[(size_t)n * HD + c8]);
                #pragma unroll
                for (int i = 0; i < 8; i++) acc[i] = bf2f(s[i]);
                int p = row_ptr[n], pe = row_ptr[n + 1];
                for (; p + 2 <= pe; p += 2) {
                    int s0 = csr[p], s1 = csr[p + 1];
                    short8v a = *reinterpret_cast<const short8v*>(&hb[(size_t)s0 * HD + c8]);
                    short8v b = *reinterpret_cast<const short8v*>(&hb[(size_t)s1 * HD + c8]);
                    #pragma unroll
                    for (int i = 0; i < 8; i++) acc[i] += bf2f(a[i]) + bf2f(b[i]);
                }
                if (p < pe) {
                    short8v a = *reinterpret_cast<const short8v*>(&hb[(size_t)csr[p] * HD + c8]);
                    #pragma unroll
                    for (int i = 0; i < 8; i++) acc[i] += bf2f(a[i]);
                }
            }
            short8v o;
            #pragma unroll
            for (int i = 0; i < 8; i++) o[i] = (short)f2bf(acc[i]);
            *reinterpret_cast<short8v*>(&As[lr * LDSW + c8]) = o;
        }
    }
    __syncthreads();

    const int wv = t >> 6, l = t & 63;
    const int l16 = l & 15, lhi = l >> 4;
    const int wrow = wv * 16;

    short8v a[4];
    #pragma unroll
    for (int kb = 0; kb < 4; kb++)
        a[kb] = *reinterpret_cast<const short8v*>(&As[(wrow + l16) * LDSW + kb * 32 + lhi * 8]);

    float4v acc[8];
    #pragma unroll
    for (int nt = 0; nt < 8; nt++) acc[nt] = (float4v){0.f, 0.f, 0.f, 0.f};

    const short8v* wp = reinterpret_cast<const short8v*>(wpackW);
    #pragma unroll
    for (int nt = 0; nt < 8; nt++) {
        #pragma unroll
        for (int kb = 0; kb < 4; kb++) {
            short8v b = wp[(nt * 4 + kb) * 64 + l];
            acc[nt] = __builtin_amdgcn_mfma_f32_16x16x32_bf16(a[kb], b, acc[nt], 0, 0, 0);
        }
    }

    #pragma unroll
    for (int nt = 0; nt < 8; nt++) {
        float bnt = bias[nt * 16 + l16];
        #pragma unroll
        for (int j = 0; j < 4; j++) {
            int r = row0 + wrow + lhi * 4 + j;
            if (r < NN) {
                float v = fmaxf(acc[nt][j] + bnt, 0.f);
                midb[(size_t)r * HD + nt * 16 + l16] = (short)f2bf(v);
            }
        }
    }
}

// ---------------------------------------------------------------------------
// GEMM2 (MFMA): Cf = midb @ W2 + b2 (f32), fused BN sums/sumsq.
// ---------------------------------------------------------------------------
__global__ __launch_bounds__(256) void gemm_b_kernel(
    const short* __restrict__ inb, const short* __restrict__ wpackW,
    const float* __restrict__ bias, float* __restrict__ Cf,
    float* __restrict__ sums, float* __restrict__ sumsq)
{
    __shared__ __align__(16) short As[64 * LDSW];
    __shared__ float redS[4][HD];
    __shared__ float redQ[4][HD];
    const int t = threadIdx.x;
    const int row0 = blockIdx.x * 64;

    {
        const int c8 = (t & 15) * 8;
        const int rg = t >> 4;
        #pragma unroll
        for (int rr = 0; rr < 4; rr++) {
            int lr = rr * 16 + rg;
            int r = row0 + lr;
            short8v v = (short8v){0,0,0,0,0,0,0,0};
            if (r < NN)
                v = *reinterpret_cast<const short8v*>(&inb[(size_t)r * HD + c8]);
            *reinterpret_cast<short8v*>(&As[lr * LDSW + c8]) = v;
        }
    }
    __syncthreads();

    const int wv = t >> 6, l = t & 63;
    const int l16 = l & 15, lhi = l >> 4;
    const int wrow = wv * 16;

    short8v a[4];
    #pragma unroll
    for (int kb = 0; kb < 4; kb++)
        a[kb] = *reinterpret_cast<const short8v*>(&As[(wrow + l16) * LDSW + kb * 32 + lhi * 8]);

    float4v acc[8];
    #pragma unroll
    for (int nt = 0; nt < 8; nt++) acc[nt] = (float4v){0.f, 0.f, 0.f, 0.f};

    const short8v* wp = reinterpret_cast<const short8v*>(wpackW);
    #pragma unroll
    for (int nt = 0; nt < 8; nt++) {
        #pragma unroll
        for (int kb = 0; kb < 4; kb++) {
            short8v b = wp[(nt * 4 + kb) * 64 + l];
            acc[nt] = __builtin_amdgcn_mfma_f32_16x16x32_bf16(a[kb], b, acc[nt], 0, 0, 0);
        }
    }

    #pragma unroll
    for (int nt = 0; nt < 8; nt++) {
        float bnt = bias[nt * 16 + l16];
        float snt = 0.f, qnt = 0.f;
        #pragma unroll
        for (int j = 0; j < 4; j++) {
            int r = row0 + wrow + lhi * 4 + j;
            if (r < NN) {
                float v = acc[nt][j] + bnt;
                Cf[(size_t)r * HD + nt * 16 + l16] = v;
                snt += v; qnt += v * v;
            }
        }
        snt += __shfl_xor(snt, 16); snt += __shfl_xor(snt, 32);
        qnt += __shfl_xor(qnt, 16); qnt += __shfl_xor(qnt, 32);
        if (lhi == 0) { redS[wv][nt * 16 + l16] = snt; redQ[wv][nt * 16 + l16] = qnt; }
    }
    __syncthreads();
    if (t < HD) {
        float ss = redS[0][t] + redS[1][t] + redS[2][t] + redS[3][t];
        float qq = redQ[0][t] + redQ[1][t] + redQ[2][t] + redQ[3][t];
        atomicAdd(&sums[t], ss);
        atomicAdd(&sumsq[t], qq);
    }
}

// ---------------------------------------------------------------------------
// CSR build: degree histogram -> 2-level exclusive scan -> slot fill.
// ---------------------------------------------------------------------------
__global__ __launch_bounds__(256) void deg_hist_kernel(
    const int* __restrict__ dst, int* __restrict__ deg)
{
    int e = blockIdx.x * 256 + threadIdx.x;
    if (e < NE) atomicAdd(&deg[dst[e]], 1);
}

__global__ __launch_bounds__(256) void scan_partial_kernel(
    const int* __restrict__ deg, int* __restrict__ bsum)
{
    __shared__ int sd[256];
    int t = threadIdx.x;
    int i = blockIdx.x * 256 + t;
    sd[t] = (i < NN) ? deg[i] : 0;
    __syncthreads();
    for (int o = 128; o > 0; o >>= 1) {
        if (t < o) sd[t] += sd[t + o];
        __syncthreads();
    }
    if (t == 0) bsum[blockIdx.x] = sd[0];
}

__global__ __launch_bounds__(256) void scan_bsums_kernel(
    const int* __restrict__ bsum, int* __restrict__ boff)
{
    __shared__ int sd[256];
    int t = threadIdx.x;
    int v = (t < NSB) ? bsum[t] : 0;
    sd[t] = v;
    __syncthreads();
    for (int o = 1; o < 256; o <<= 1) {
        int x = (t >= o) ? sd[t - o] : 0;
        __syncthreads();
        sd[t] += x;
        __syncthreads();
    }
    if (t < NSB) boff[t] = sd[t] - v;   // exclusive
}

__global__ __launch_bounds__(256) void scan_final_kernel(
    const int* __restrict__ deg, const int* __restrict__ boff,
    int* __restrict__ row_ptr, int* __restrict__ cursor)
{
    __shared__ int sd[256];
    int t = threadIdx.x;
    int i = blockIdx.x * 256 + t;
    int v = (i < NN) ? deg[i] : 0;
    sd[t] = v;
    __syncthreads();
    for (int o = 1; o < 256; o <<= 1) {
        int x = (t >= o) ? sd[t - o] : 0;
        __syncthreads();
        sd[t] += x;
        __syncthreads();
    }
    int excl = sd[t] - v + boff[blockIdx.x];
    if (i < NN) { row_ptr[i] = excl; cursor[i] = excl; }
    if (i == NN - 1) row_ptr[NN] = excl + v;   // == NE
}

__global__ __launch_bounds__(256) void fill_csr_kernel(
    const int* __restrict__ src, const int* __restrict__ dst,
    int* __restrict__ cursor, int* __restrict__ csr)
{
    int e = blockIdx.x * 256 + threadIdx.x;
    if (e >= NE) return;
    int p = atomicAdd(&cursor[dst[e]], 1);
    csr[p] = src[e];
}

// ---------------------------------------------------------------------------
// BN apply: computes scale/shift in-block from sums/sumsq, then
// relu(C*scale + shift) -> bf16 hb.
// ---------------------------------------------------------------------------
__global__ __launch_bounds__(256) void bn_apply_kernel(
    const float* __restrict__ C, const float* __restrict__ sums,
    const float* __restrict__ sumsq, const float* __restrict__ gamma,
    const float* __restrict__ beta, short* __restrict__ hb)
{
    __shared__ float sscale[HD];
    __shared__ float sshift[HD];
    int t = threadIdx.x;
    if (t < HD) {
        const float invN = 1.f / (float)NN;
        float mean = sums[t] * invN;
        float var = sumsq[t] * invN - mean * mean;
        float inv = rsqrtf(var + BN_EPS);
        float sc = gamma[t] * inv;
        sscale[t] = sc;
        sshift[t] = beta[t] - mean * sc;
    }
    __syncthreads();
    int idx = blockIdx.x * 256 + t;
    if (idx >= NN * 32) return;
    float4 v = reinterpret_cast<const float4*>(C)[idx];
    int c0 = (idx & 31) * 4;
    v.x = fmaxf(v.x * sscale[c0 + 0] + sshift[c0 + 0], 0.f);
    v.y = fmaxf(v.y * sscale[c0 + 1] + sshift[c0 + 1], 0.f);
    v.z = fmaxf(v.z * sscale[c0 + 2] + sshift[c0 + 2], 0.f);
    v.w = fmaxf(v.w * sscale[c0 + 3] + sshift[c0 + 3], 0.f);
    short4 o = make_short4((short)f2bf(v.x), (short)f2bf(v.y),
                           (short)f2bf(v.z), (short)f2bf(v.w));
    reinterpret_cast<short4*>(hb)[idx] = o;
}

// ---------------------------------------------------------------------------
// Pool v3: one block per graph (sorted batch -> contiguous range via binary
// search), f32 reg accumulate, LDS reduce, direct store. Zero atomics.
// ---------------------------------------------------------------------------
__global__ __launch_bounds__(256) void pool_kernel_v3(
    const short* __restrict__ hb, const int* __restrict__ batch,
    float* __restrict__ g)
{
    const int gr = blockIdx.x;
    int lo = 0, hi = NN;
    while (lo < hi) { int m = (lo + hi) >> 1; if (batch[m] < gr) lo = m + 1; else hi = m; }
    const int start = lo;
    hi = NN;
    while (lo < hi) { int m = (lo + hi) >> 1; if (batch[m] <= gr) lo = m + 1; else hi = m; }
    const int end = lo;

    const int cg = threadIdx.x & 15;   // cols cg*8..cg*8+7
    const int rg = threadIdx.x >> 4;   // row group 0..15
    float acc[8] = {0, 0, 0, 0, 0, 0, 0, 0};
    for (int r = start + rg; r < end; r += 16) {
        short8v v = *reinterpret_cast<const short8v*>(&hb[(size_t)r * HD + cg * 8]);
        #pragma unroll
        for (int i = 0; i < 8; i++) acc[i] += bf2f(v[i]);
    }
    __shared__ float red[16][HD];
    #pragma unroll
    for (int i = 0; i < 8; i++) red[rg][cg * 8 + i] = acc[i];
    __syncthreads();
    if (threadIdx.x < HD) {
        float s = 0.f;
        #pragma unroll
        for (int k = 0; k < 16; k++) s += red[k][threadIdx.x];
        g[gr * HD + threadIdx.x] = s;
    }
}

// ---------------------------------------------------------------------------
// Fused final MLP: out[r,:] = relu(g[r,:]@Wf1+bf1) @ Wf2 + bf2. Block per row.
// ---------------------------------------------------------------------------
__global__ __launch_bounds__(128) void final_kernel(
    const float* __restrict__ g, const float* __restrict__ Wf1,
    const float* __restrict__ bf1, const float* __restrict__ Wf2,
    const float* __restrict__ bf2, float* __restrict__ out)
{
    __shared__ float gr[HD];
    __shared__ float yr[HD];
    int r = blockIdx.x, c = threadIdx.x;
    gr[c] = g[r * HD + c];
    __syncthreads();
    float acc = bf1[c];
    for (int k = 0; k < HD; k++) acc += gr[k] * Wf1[k * HD + c];
    yr[c] = fmaxf(acc, 0.f);
    __syncthreads();
    if (c < OUTF) {
        float o = bf2[c];
        for (int k = 0; k < HD; k++) o += yr[k] * Wf2[k * OUTF + c];
        out[r * OUTF + c] = o;
    }
}

// ---------------------------------------------------------------------------
extern "C" void kernel_launch(void* const* d_in, const int* in_sizes, int n_in,
                              void* d_out, int out_size, void* d_ws, size_t ws_size,
                              hipStream_t stream)
{
    const float* x     = (const float*)d_in[0];
    const int*   ei    = (const int*)  d_in[1];
    const int*   batch = (const int*)  d_in[2];
    const float* W1    = (const float*)d_in[3];
    const float* b1    = (const float*)d_in[4];
    const float* W2    = (const float*)d_in[5];
    const float* b2    = (const float*)d_in[6];
    const float* gamma = (const float*)d_in[7];
    const float* beta  = (const float*)d_in[8];
    const float* Wf1   = (const float*)d_in[9];
    const float* bf1   = (const float*)d_in[10];
    const float* Wf2   = (const float*)d_in[11];
    const float* bf2   = (const float*)d_in[12];
    float* out = (float*)d_out;

    float* ws   = (float*)d_ws;
    const size_t BIG = (size_t)NN * HD;       // 6.4M elems
    float* Cbuf = ws;                         // f32 pre-BN C
    short* hb   = (short*)(ws + BIG);         // bf16 h
    short* midb = (short*)(ws + 2 * BIG);     // bf16 mid
    float* smal = ws + 3 * BIG;
    float* sums  = smal;                      // 128
    float* sumsq = smal + 128;                // 128 (contiguous with sums)
    float* gpool = smal + 512;                // 128*128
    int* ip      = (int*)(smal + 65536);
    int* deg     = ip;                        // NN
    int* row_ptr = ip + NN;                   // NN+1
    int* cursor  = row_ptr + NN + 1;          // NN
    int* bsum    = cursor + NN;               // 256
    int* boff    = bsum + 256;                // 256
    int* csr     = boff + 256;                // NE
    short* wpack = (short*)(csr + NE);        // 8 * 16384 bf16

    const int* src = ei;
    const int* dst = ei + NE;

    const int gemm_grid = (NN + 63) / 64;         // 782
    const int bn_grid   = (NN * 32 + 255) / 256;  // 6250
    const int edge_grid = (NE + 255) / 256;       // 2344

    // ---- one-time per launch: W pre-pack + x->bf16 + CSR build ----
    pack_w_kernel<<<64, 256, 0, stream>>>(W1, W2, wpack);
    cvt_bf16_kernel<<<bn_grid, 256, 0, stream>>>(x, hb);
    hipMemsetAsync(deg, 0, NN * sizeof(int), stream);
    deg_hist_kernel<<<edge_grid, 256, 0, stream>>>(dst, deg);
    scan_partial_kernel<<<NSB, 256, 0, stream>>>(deg, bsum);
    scan_bsums_kernel<<<1, 256, 0, stream>>>(bsum, boff);
    scan_final_kernel<<<NSB, 256, 0, stream>>>(deg, boff, row_ptr, cursor);
    fill_csr_kernel<<<edge_grid, 256, 0, stream>>>(src, dst, cursor, csr);

    for (int l = 0; l < NL; l++) {
        gemm_ag_kernel<<<gemm_grid, 256, 0, stream>>>(
            hb, row_ptr, csr, wpack + (size_t)(l * 2 + 0) * 16384,
            b1 + l * HD, midb, sums);
        gemm_b_kernel<<<gemm_grid, 256, 0, stream>>>(
            midb, wpack + (size_t)(l * 2 + 1) * 16384, b2 + l * HD,
            Cbuf, sums, sumsq);
        bn_apply_kernel<<<bn_grid, 256, 0, stream>>>(
            Cbuf, sums, sumsq, gamma + l * HD, beta + l * HD, hb);
    }

    pool_kernel_v3<<<NG, 256, 0, stream>>>(hb, batch, gpool);
    final_kernel<<<NG, 128, 0, stream>>>(gpool, Wf1, bf1, Wf2, bf2, out);
}

// Round 10
// 383.978 us; speedup vs baseline: 12.1500x; 1.1371x over previous
//
#include <hip/hip_runtime.h>

#define NN 50000
#define NE 600000
#define HD 128
#define OUTF 64
#define NL 4
#define NG 128
#define BN_EPS 1e-5f
#define NSB 196   // ceil(NN/256) scan blocks

typedef __attribute__((ext_vector_type(8))) short short8v;
typedef __attribute__((ext_vector_type(4))) float float4v;

#define LDSW 136   // padded LDS row stride in bf16 elems

__device__ inline unsigned short f2bf(float f) {   // RNE f32->bf16 (finite inputs)
    unsigned int u = __float_as_uint(f);
    return (unsigned short)((u + 0x7FFF + ((u >> 16) & 1)) >> 16);
}
__device__ inline float bf2f(short s) {
    return __uint_as_float(((unsigned int)(unsigned short)s) << 16);
}

// ---------------------------------------------------------------------------
// W pre-pack + stats zero: wpack[w][nt][kb][lane][i] layout as before.
// Threads 0..255 of block 0 also zero the 4 per-layer stats buffers (1024 f).
// ---------------------------------------------------------------------------
__global__ __launch_bounds__(256) void pack_w_kernel(
    const float* __restrict__ W1, const float* __restrict__ W2,
    short* __restrict__ wpack, float* __restrict__ stats4)
{
    int gid = blockIdx.x * 256 + threadIdx.x;    // 8*8*4*64 = 16384
    if (gid < 256)
        reinterpret_cast<float4*>(stats4)[gid] = (float4){0.f, 0.f, 0.f, 0.f};
    int l  = gid & 63;
    int kb = (gid >> 6) & 3;
    int nt = (gid >> 8) & 7;
    int w  = gid >> 11;                          // 0..7
    const float* W = (w & 1) ? (W2 + (size_t)(w >> 1) * HD * HD)
                             : (W1 + (size_t)(w >> 1) * HD * HD);
    int col  = nt * 16 + (l & 15);
    int krow = kb * 32 + (l >> 4) * 8;
    short* o = wpack + (size_t)w * 16384 + ((size_t)(nt * 4 + kb) * 64 + l) * 8;
    #pragma unroll
    for (int i = 0; i < 8; i++)
        o[i] = (short)f2bf(W[(size_t)(krow + i) * HD + col]);
}

// x (f32) -> hb (bf16), one-time.
__global__ __launch_bounds__(256) void cvt_bf16_kernel(
    const float* __restrict__ x, short* __restrict__ hb)
{
    int idx = blockIdx.x * 256 + threadIdx.x;
    if (idx >= NN * 32) return;
    float4 v = reinterpret_cast<const float4*>(x)[idx];
    short4 o = make_short4((short)f2bf(v.x), (short)f2bf(v.y),
                           (short)f2bf(v.z), (short)f2bf(v.w));
    reinterpret_cast<short4*>(hb)[idx] = o;
}

// ---------------------------------------------------------------------------
// Fused GIN layer kernel (one 64-row tile per block):
//  1) gather:  As = bf16( hb[n] + sum_{j in N(n)} hb[j] )      (LDS)
//  2) MFMA1:   mid = relu(As @ W1 + b1)  -> bf16 back into As  (LDS round-trip)
//  3) MFMA2:   C   = mid @ W2 + b2       -> bf16 Cb (global) + f32 col stats
// ---------------------------------------------------------------------------
__global__ __launch_bounds__(256) void layer_kernel(
    const short* __restrict__ hb, const int* __restrict__ row_ptr,
    const int* __restrict__ csr, const short* __restrict__ wp1,
    const float* __restrict__ b1, const short* __restrict__ wp2,
    const float* __restrict__ b2, short* __restrict__ Cb,
    float* __restrict__ sums, float* __restrict__ sumsq)
{
    __shared__ __align__(16) short As[64 * LDSW];
    const int t = threadIdx.x;
    const int row0 = blockIdx.x * 64;

    // ---- 1) gather stage: 16 lanes per node, 16 nodes per iteration ----
    {
        const int ng = t >> 4;          // 0..15
        const int c8 = (t & 15) * 8;
        #pragma unroll
        for (int it = 0; it < 4; it++) {
            int lr = it * 16 + ng;
            int n = row0 + lr;
            float acc[8] = {0, 0, 0, 0, 0, 0, 0, 0};
            if (n < NN) {
                short8v s = *reinterpret_cast<const short8v*>(&hb[(size_t)n * HD + c8]);
                #pragma unroll
                for (int i = 0; i < 8; i++) acc[i] = bf2f(s[i]);
                int p = row_ptr[n], pe = row_ptr[n + 1];
                for (; p + 2 <= pe; p += 2) {
                    int s0 = csr[p], s1 = csr[p + 1];
                    short8v a = *reinterpret_cast<const short8v*>(&hb[(size_t)s0 * HD + c8]);
                    short8v b = *reinterpret_cast<const short8v*>(&hb[(size_t)s1 * HD + c8]);
                    #pragma unroll
                    for (int i = 0; i < 8; i++) acc[i] += bf2f(a[i]) + bf2f(b[i]);
                }
                if (p < pe) {
                    short8v a = *reinterpret_cast<const short8v*>(&hb[(size_t)csr[p] * HD + c8]);
                    #pragma unroll
                    for (int i = 0; i < 8; i++) acc[i] += bf2f(a[i]);
                }
            }
            short8v o;
            #pragma unroll
            for (int i = 0; i < 8; i++) o[i] = (short)f2bf(acc[i]);
            *reinterpret_cast<short8v*>(&As[lr * LDSW + c8]) = o;
        }
    }
    __syncthreads();

    const int wv = t >> 6, l = t & 63;
    const int l16 = l & 15, lhi = l >> 4;
    const int wrow = wv * 16;

    // ---- 2) MFMA1 ----
    short8v a[4];
    #pragma unroll
    for (int kb = 0; kb < 4; kb++)
        a[kb] = *reinterpret_cast<const short8v*>(&As[(wrow + l16) * LDSW + kb * 32 + lhi * 8]);
    __syncthreads();   // all a1-frags loaded; As free for mid

    float4v acc[8];
    #pragma unroll
    for (int nt = 0; nt < 8; nt++) acc[nt] = (float4v){0.f, 0.f, 0.f, 0.f};
    {
        const short8v* wp = reinterpret_cast<const short8v*>(wp1);
        #pragma unroll
        for (int nt = 0; nt < 8; nt++) {
            #pragma unroll
            for (int kb = 0; kb < 4; kb++) {
                short8v b = wp[(nt * 4 + kb) * 64 + l];
                acc[nt] = __builtin_amdgcn_mfma_f32_16x16x32_bf16(a[kb], b, acc[nt], 0, 0, 0);
            }
        }
    }
    // relu + bf16 -> mid tile back into As
    #pragma unroll
    for (int nt = 0; nt < 8; nt++) {
        float bnt = b1[nt * 16 + l16];
        #pragma unroll
        for (int j = 0; j < 4; j++) {
            float v = fmaxf(acc[nt][j] + bnt, 0.f);
            As[(wrow + lhi * 4 + j) * LDSW + nt * 16 + l16] = (short)f2bf(v);
        }
    }
    __syncthreads();

    // ---- 3) MFMA2 ----
    #pragma unroll
    for (int kb = 0; kb < 4; kb++)
        a[kb] = *reinterpret_cast<const short8v*>(&As[(wrow + l16) * LDSW + kb * 32 + lhi * 8]);

    #pragma unroll
    for (int nt = 0; nt < 8; nt++) acc[nt] = (float4v){0.f, 0.f, 0.f, 0.f};
    {
        const short8v* wp = reinterpret_cast<const short8v*>(wp2);
        #pragma unroll
        for (int nt = 0; nt < 8; nt++) {
            #pragma unroll
            for (int kb = 0; kb < 4; kb++) {
                short8v b = wp[(nt * 4 + kb) * 64 + l];
                acc[nt] = __builtin_amdgcn_mfma_f32_16x16x32_bf16(a[kb], b, acc[nt], 0, 0, 0);
            }
        }
    }

    // epilogue: write bf16 Cb + per-column stats (reuse As as f32 scratch)
    __syncthreads();   // all a2-frags consumed; As free for reduction
    float* redS = reinterpret_cast<float*>(As);          // [4][128]
    float* redQ = redS + 4 * HD;                         // [4][128]
    #pragma unroll
    for (int nt = 0; nt < 8; nt++) {
        float bnt = b2[nt * 16 + l16];
        float snt = 0.f, qnt = 0.f;
        #pragma unroll
        for (int j = 0; j < 4; j++) {
            int r = row0 + wrow + lhi * 4 + j;
            if (r < NN) {
                float v = acc[nt][j] + bnt;
                Cb[(size_t)r * HD + nt * 16 + l16] = (short)f2bf(v);
                snt += v; qnt += v * v;
            }
        }
        snt += __shfl_xor(snt, 16); snt += __shfl_xor(snt, 32);
        qnt += __shfl_xor(qnt, 16); qnt += __shfl_xor(qnt, 32);
        if (lhi == 0) { redS[wv * HD + nt * 16 + l16] = snt; redQ[wv * HD + nt * 16 + l16] = qnt; }
    }
    __syncthreads();
    if (t < HD) {
        float ss = redS[0 * HD + t] + redS[1 * HD + t] + redS[2 * HD + t] + redS[3 * HD + t];
        float qq = redQ[0 * HD + t] + redQ[1 * HD + t] + redQ[2 * HD + t] + redQ[3 * HD + t];
        atomicAdd(&sums[t], ss);
        atomicAdd(&sumsq[t], qq);
    }
}

// ---------------------------------------------------------------------------
// CSR build: degree histogram -> 2-level exclusive scan -> slot fill.
// ---------------------------------------------------------------------------
__global__ __launch_bounds__(256) void deg_hist_kernel(
    const int* __restrict__ dst, int* __restrict__ deg)
{
    int e = blockIdx.x * 256 + threadIdx.x;
    if (e < NE) atomicAdd(&deg[dst[e]], 1);
}

__global__ __launch_bounds__(256) void scan_partial_kernel(
    const int* __restrict__ deg, int* __restrict__ bsum)
{
    __shared__ int sd[256];
    int t = threadIdx.x;
    int i = blockIdx.x * 256 + t;
    sd[t] = (i < NN) ? deg[i] : 0;
    __syncthreads();
    for (int o = 128; o > 0; o >>= 1) {
        if (t < o) sd[t] += sd[t + o];
        __syncthreads();
    }
    if (t == 0) bsum[blockIdx.x] = sd[0];
}

__global__ __launch_bounds__(256) void scan_bsums_kernel(
    const int* __restrict__ bsum, int* __restrict__ boff)
{
    __shared__ int sd[256];
    int t = threadIdx.x;
    int v = (t < NSB) ? bsum[t] : 0;
    sd[t] = v;
    __syncthreads();
    for (int o = 1; o < 256; o <<= 1) {
        int x = (t >= o) ? sd[t - o] : 0;
        __syncthreads();
        sd[t] += x;
        __syncthreads();
    }
    if (t < NSB) boff[t] = sd[t] - v;   // exclusive
}

__global__ __launch_bounds__(256) void scan_final_kernel(
    const int* __restrict__ deg, const int* __restrict__ boff,
    int* __restrict__ row_ptr, int* __restrict__ cursor)
{
    __shared__ int sd[256];
    int t = threadIdx.x;
    int i = blockIdx.x * 256 + t;
    int v = (i < NN) ? deg[i] : 0;
    sd[t] = v;
    __syncthreads();
    for (int o = 1; o < 256; o <<= 1) {
        int x = (t >= o) ? sd[t - o] : 0;
        __syncthreads();
        sd[t] += x;
        __syncthreads();
    }
    int excl = sd[t] - v + boff[blockIdx.x];
    if (i < NN) { row_ptr[i] = excl; cursor[i] = excl; }
    if (i == NN - 1) row_ptr[NN] = excl + v;   // == NE
}

__global__ __launch_bounds__(256) void fill_csr_kernel(
    const int* __restrict__ src, const int* __restrict__ dst,
    int* __restrict__ cursor, int* __restrict__ csr)
{
    int e = blockIdx.x * 256 + threadIdx.x;
    if (e >= NE) return;
    int p = atomicAdd(&cursor[dst[e]], 1);
    csr[p] = src[e];
}

// ---------------------------------------------------------------------------
// BN apply: scale/shift computed in-block from stats, reads bf16 Cb,
// writes relu-normalized bf16 hb. 8 elems per thread.
// ---------------------------------------------------------------------------
__global__ __launch_bounds__(256) void bn_apply_kernel(
    const short* __restrict__ Cb, const float* __restrict__ sums,
    const float* __restrict__ sumsq, const float* __restrict__ gamma,
    const float* __restrict__ beta, short* __restrict__ hb)
{
    __shared__ float sscale[HD];
    __shared__ float sshift[HD];
    int t = threadIdx.x;
    if (t < HD) {
        const float invN = 1.f / (float)NN;
        float mean = sums[t] * invN;
        float var = sumsq[t] * invN - mean * mean;
        float inv = rsqrtf(var + BN_EPS);
        float sc = gamma[t] * inv;
        sscale[t] = sc;
        sshift[t] = beta[t] - mean * sc;
    }
    __syncthreads();
    int idx = blockIdx.x * 256 + t;
    if (idx >= NN * 16) return;
    short8v v = reinterpret_cast<const short8v*>(Cb)[idx];
    int c0 = (idx & 15) * 8;
    short8v o;
    #pragma unroll
    for (int i = 0; i < 8; i++) {
        float f = fmaxf(bf2f(v[i]) * sscale[c0 + i] + sshift[c0 + i], 0.f);
        o[i] = (short)f2bf(f);
    }
    reinterpret_cast<short8v*>(hb)[idx] = o;
}

// ---------------------------------------------------------------------------
// Pool v3: one block per graph (sorted batch -> contiguous range via binary
// search), f32 reg accumulate, LDS reduce, direct store. Zero atomics.
// ---------------------------------------------------------------------------
__global__ __launch_bounds__(256) void pool_kernel_v3(
    const short* __restrict__ hb, const int* __restrict__ batch,
    float* __restrict__ g)
{
    const int gr = blockIdx.x;
    int lo = 0, hi = NN;
    while (lo < hi) { int m = (lo + hi) >> 1; if (batch[m] < gr) lo = m + 1; else hi = m; }
    const int start = lo;
    hi = NN;
    while (lo < hi) { int m = (lo + hi) >> 1; if (batch[m] <= gr) lo = m + 1; else hi = m; }
    const int end = lo;

    const int cg = threadIdx.x & 15;   // cols cg*8..cg*8+7
    const int rg = threadIdx.x >> 4;   // row group 0..15
    float acc[8] = {0, 0, 0, 0, 0, 0, 0, 0};
    for (int r = start + rg; r < end; r += 16) {
        short8v v = *reinterpret_cast<const short8v*>(&hb[(size_t)r * HD + cg * 8]);
        #pragma unroll
        for (int i = 0; i < 8; i++) acc[i] += bf2f(v[i]);
    }
    __shared__ float red[16][HD];
    #pragma unroll
    for (int i = 0; i < 8; i++) red[rg][cg * 8 + i] = acc[i];
    __syncthreads();
    if (threadIdx.x < HD) {
        float s = 0.f;
        #pragma unroll
        for (int k = 0; k < 16; k++) s += red[k][threadIdx.x];
        g[gr * HD + threadIdx.x] = s;
    }
}

// ---------------------------------------------------------------------------
// Fused final MLP: out[r,:] = relu(g[r,:]@Wf1+bf1) @ Wf2 + bf2. Block per row.
// ---------------------------------------------------------------------------
__global__ __launch_bounds__(128) void final_kernel(
    const float* __restrict__ g, const float* __restrict__ Wf1,
    const float* __restrict__ bf1, const float* __restrict__ Wf2,
    const float* __restrict__ bf2, float* __restrict__ out)
{
    __shared__ float gr[HD];
    __shared__ float yr[HD];
    int r = blockIdx.x, c = threadIdx.x;
    gr[c] = g[r * HD + c];
    __syncthreads();
    float acc = bf1[c];
    for (int k = 0; k < HD; k++) acc += gr[k] * Wf1[k * HD + c];
    yr[c] = fmaxf(acc, 0.f);
    __syncthreads();
    if (c < OUTF) {
        float o = bf2[c];
        for (int k = 0; k < HD; k++) o += yr[k] * Wf2[k * OUTF + c];
        out[r * OUTF + c] = o;
    }
}

// ---------------------------------------------------------------------------
extern "C" void kernel_launch(void* const* d_in, const int* in_sizes, int n_in,
                              void* d_out, int out_size, void* d_ws, size_t ws_size,
                              hipStream_t stream)
{
    const float* x     = (const float*)d_in[0];
    const int*   ei    = (const int*)  d_in[1];
    const int*   batch = (const int*)  d_in[2];
    const float* W1    = (const float*)d_in[3];
    const float* b1    = (const float*)d_in[4];
    const float* W2    = (const float*)d_in[5];
    const float* b2    = (const float*)d_in[6];
    const float* gamma = (const float*)d_in[7];
    const float* beta  = (const float*)d_in[8];
    const float* Wf1   = (const float*)d_in[9];
    const float* bf1   = (const float*)d_in[10];
    const float* Wf2   = (const float*)d_in[11];
    const float* bf2   = (const float*)d_in[12];
    float* out = (float*)d_out;

    float* ws   = (float*)d_ws;
    const size_t BIG = (size_t)NN * HD;       // 6.4M elems
    short* Cb   = (short*)ws;                 // bf16 pre-BN C (BIG shorts)
    short* hb   = (short*)(ws + BIG);         // bf16 h
    float* smal = ws + 3 * BIG;
    float* stats4 = smal;                     // 4 layers x (sums 128 + sumsq 128)
    float* gpool  = smal + 2048;              // 128*128
    int* ip      = (int*)(smal + 65536);
    int* deg     = ip;                        // NN
    int* row_ptr = ip + NN;                   // NN+1
    int* cursor  = row_ptr + NN + 1;          // NN
    int* bsum    = cursor + NN;               // 256
    int* boff    = bsum + 256;                // 256
    int* csr     = boff + 256;                // NE
    short* wpack = (short*)(csr + NE);        // 8 * 16384 bf16

    const int* src = ei;
    const int* dst = ei + NE;

    const int gemm_grid = (NN + 63) / 64;         // 782
    const int cvt_grid  = (NN * 32 + 255) / 256;  // 6250
    const int bn_grid   = (NN * 16 + 255) / 256;  // 3125
    const int edge_grid = (NE + 255) / 256;       // 2344

    // ---- one-time per launch: W pre-pack (+stats zero) + x->bf16 + CSR ----
    pack_w_kernel<<<64, 256, 0, stream>>>(W1, W2, wpack, stats4);
    cvt_bf16_kernel<<<cvt_grid, 256, 0, stream>>>(x, hb);
    hipMemsetAsync(deg, 0, NN * sizeof(int), stream);
    deg_hist_kernel<<<edge_grid, 256, 0, stream>>>(dst, deg);
    scan_partial_kernel<<<NSB, 256, 0, stream>>>(deg, bsum);
    scan_bsums_kernel<<<1, 256, 0, stream>>>(bsum, boff);
    scan_final_kernel<<<NSB, 256, 0, stream>>>(deg, boff, row_ptr, cursor);
    fill_csr_kernel<<<edge_grid, 256, 0, stream>>>(src, dst, cursor, csr);

    for (int l = 0; l < NL; l++) {
        float* sums  = stats4 + l * 256;
        float* sumsq = sums + 128;
        layer_kernel<<<gemm_grid, 256, 0, stream>>>(
            hb, row_ptr, csr,
            wpack + (size_t)(l * 2 + 0) * 16384, b1 + l * HD,
            wpack + (size_t)(l * 2 + 1) * 16384, b2 + l * HD,
            Cb, sums, sumsq);
        bn_apply_kernel<<<bn_grid, 256, 0, stream>>>(
            Cb, sums, sumsq, gamma + l * HD, beta + l * HD, hb);
    }

    pool_kernel_v3<<<NG, 256, 0, stream>>>(hb, batch, gpool);
    final_kernel<<<NG, 128, 0, stream>>>(gpool, Wf1, bf1, Wf2, bf2, out);
}